// Round 7
// baseline (218.720 us; speedup 1.0000x reference)
//
#include <hip/hip_runtime.h>
#include <hip/hip_bf16.h>

typedef __bf16 bf16;
typedef unsigned int u32;
typedef __attribute__((ext_vector_type(4))) float f32x4;
typedef __attribute__((ext_vector_type(16))) float f32x16;
typedef __attribute__((ext_vector_type(8))) bf16 bf16x8;
typedef __attribute__((ext_vector_type(4))) bf16 bf16x4;
typedef __attribute__((ext_vector_type(4))) u32 u32x4;

#define GPTR(p) ((const __attribute__((address_space(1))) u32*)(p))
#define SPTR(p) ((__attribute__((address_space(3))) u32*)(p))

// Problem constants
constexpr int BATCH = 2, SEQ = 2048, DMODEL = 1024, NH = 16, HD = 64, QKV3 = 3072;
constexpr int MTOK = BATCH * SEQ;  // 4096 tokens

// Workspace layout (bytes)
constexpr size_t OXB = 0;                                       // X bf16 [4096][1024]
constexpr size_t OWQ = OXB + (size_t)MTOK * DMODEL * 2;         // Wqkv^T bf16 [3072][1024]
constexpr size_t OWO = OWQ + (size_t)QKV3 * DMODEL * 2;         // Wout^T bf16 [1024][1024]
constexpr size_t OCS = OWO + (size_t)DMODEL * DMODEL * 2;       // cos/sin f32 [2048][32][2]
constexpr size_t OCQ = OCS + (size_t)SEQ * 32 * 8;              // C_qkv bf16 [4096][3072]
constexpr size_t OQR = OCQ + (size_t)MTOK * QKV3 * 2;           // Q roped [b][h][n][64]
constexpr size_t OKR = OQR + (size_t)BATCH * NH * SEQ * HD * 2; // K roped
constexpr size_t OVT = OKR + (size_t)BATCH * NH * SEQ * HD * 2; // V^T [b][h][64][n]
constexpr size_t OAO = OXB;                                     // attn out (aliases Xb, dead by then)

static __device__ __forceinline__ bf16 tobf(float x) { return (bf16)x; }
static __device__ __forceinline__ float tof(bf16 x) { return (float)x; }

static __device__ __forceinline__ f32x4 mfma16(bf16x8 a, bf16x8 b, f32x4 c) {
  return __builtin_amdgcn_mfma_f32_16x16x32_bf16(a, b, c, 0, 0, 0);
}
static __device__ __forceinline__ f32x16 mfma32(bf16x8 a, bf16x8 b, f32x16 c) {
  return __builtin_amdgcn_mfma_f32_32x32x16_bf16(a, b, c, 0, 0, 0);
}

// ---------------- prep kernels ----------------

__global__ void k_costab(float* __restrict__ cs) {
  int idx = blockIdx.x * 256 + threadIdx.x;  // 65536 = 2048*32
  int n = idx >> 5, i = idx & 31;
  float freq = powf(10000.0f, -(float)(2 * i) / 64.0f);
  float ang = (float)n * freq;
  float s, c;
  sincosf(ang, &s, &c);
  cs[idx * 2] = c;
  cs[idx * 2 + 1] = s;
}

__global__ void k_cvt(const float* __restrict__ x, bf16* __restrict__ y, int n4) {
  int i = blockIdx.x * 256 + threadIdx.x;
  if (i >= n4) return;
  float4 v = ((const float4*)x)[i];
  bf16x4 o = {tobf(v.x), tobf(v.y), tobf(v.z), tobf(v.w)};
  ((bf16x4*)y)[i] = o;
}

// transpose-convert: in f32 [R][C] -> out bf16 [C][R]
__global__ void k_trans(const float* __restrict__ in, bf16* __restrict__ out, int R, int C) {
  __shared__ float tile[32][33];
  int k0 = blockIdx.y * 32, n0 = blockIdx.x * 32;
  int tx = threadIdx.x & 31, ty = threadIdx.x >> 5;  // ty 0..7
#pragma unroll
  for (int r = ty; r < 32; r += 8) tile[r][tx] = in[(size_t)(k0 + r) * C + n0 + tx];
  __syncthreads();
#pragma unroll
  for (int r = ty; r < 32; r += 8) out[(size_t)(n0 + r) * R + k0 + tx] = tobf(tile[tx][r]);
}

// ---------------- GEMM: A bf16 [M][K] x Bt bf16 [N][K] -> C ----------------
// 128x128 tile, BK=32, double-buffered LDS, 2-phase loop: one barrier/iter,
// staging loads for t+1 fly under tile t's ds_read+MFMA. XCD-swizzled grid.

template <int BF16OUT>
__global__ __launch_bounds__(256) void k_gemm(const bf16* __restrict__ A, const bf16* __restrict__ Bt,
                                              void* __restrict__ Cout, const float* __restrict__ bias,
                                              int M, int Nn, int K) {
  __shared__ __attribute__((aligned(16))) char smem[32768];  // 2 x (As 8KB | Bs 8KB)
  const int nTn = Nn >> 7;
  int nwg = gridDim.x;
  int bid = blockIdx.x;
  int wgs = (bid & 7) * (nwg >> 3) + (bid >> 3);  // bijective XCD swizzle (nwg%8==0)
  const int m0 = (wgs / nTn) << 7;
  const int n0 = (wgs % nTn) << 7;
  const int tid = threadIdx.x;
  const int lane = tid & 63, w = tid >> 6;
  const int wr = w >> 1, wc = w & 1;
  const int l15 = lane & 15, lhi = lane >> 4;
  f32x4 acc[4][4] = {};

  const int flat0 = w * 1024 + lane * 16;  // byte offset in 8KB half-tile
  const int flat1 = flat0 + 4096;
  const int row0 = flat0 >> 6, ke0 = (flat0 & 63) >> 1;
  const int row1 = flat1 >> 6, ke1 = (flat1 & 63) >> 1;

#define GSTAGE(bb_, k0_)                                                                       \
  do {                                                                                         \
    __builtin_amdgcn_global_load_lds(GPTR(A + (size_t)(m0 + row0) * K + (k0_) + ke0),          \
                                     SPTR(smem + (bb_)*16384 + flat0), 16, 0, 0);              \
    __builtin_amdgcn_global_load_lds(GPTR(A + (size_t)(m0 + row1) * K + (k0_) + ke1),          \
                                     SPTR(smem + (bb_)*16384 + flat1), 16, 0, 0);              \
    __builtin_amdgcn_global_load_lds(GPTR(Bt + (size_t)(n0 + row0) * K + (k0_) + ke0),         \
                                     SPTR(smem + (bb_)*16384 + 8192 + flat0), 16, 0, 0);       \
    __builtin_amdgcn_global_load_lds(GPTR(Bt + (size_t)(n0 + row1) * K + (k0_) + ke1),         \
                                     SPTR(smem + (bb_)*16384 + 8192 + flat1), 16, 0, 0);       \
  } while (0)

  GSTAGE(0, 0);
  const int nIt = K >> 5;
  for (int it = 0; it < nIt; ++it) {
    asm volatile("s_waitcnt vmcnt(0)" ::: "memory");  // tile it staged
    __builtin_amdgcn_s_barrier();                     // prev reads done; tile it visible
    if (it + 1 < nIt) GSTAGE((it + 1) & 1, (it + 1) << 5);
    const bf16* As = (const bf16*)(smem + (it & 1) * 16384);
    const bf16* Bs = (const bf16*)(smem + (it & 1) * 16384 + 8192);
    bf16x8 af[4], bfv[4];
#pragma unroll
    for (int i = 0; i < 4; ++i) {
      af[i] = *(const bf16x8*)(As + (wr * 64 + i * 16 + l15) * 32 + lhi * 8);
      bfv[i] = *(const bf16x8*)(Bs + (wc * 64 + i * 16 + l15) * 32 + lhi * 8);
    }
    __builtin_amdgcn_s_setprio(1);
#pragma unroll
    for (int i = 0; i < 4; ++i)
#pragma unroll
      for (int j = 0; j < 4; ++j) acc[i][j] = mfma16(af[i], bfv[j], acc[i][j]);
    __builtin_amdgcn_s_setprio(0);
  }
#undef GSTAGE

  if constexpr (BF16OUT) {
    __syncthreads();  // all waves done with last tile's LDS before overlay
    bf16* Cs = (bf16*)smem;  // [128][128]
#pragma unroll
    for (int i = 0; i < 4; ++i)
#pragma unroll
      for (int j = 0; j < 4; ++j) {
        int row = wr * 64 + i * 16 + lhi * 4;
        int col = wc * 64 + j * 16 + l15;
#pragma unroll
        for (int r = 0; r < 4; ++r) Cs[(row + r) * 128 + col] = tobf(acc[i][j][r]);
      }
    __syncthreads();
    bf16* C = (bf16*)Cout;
#pragma unroll
    for (int inst = 0; inst < 8; ++inst) {
      int flat = inst * 4096 + tid * 16;  // bytes over 32KB
      int row = flat >> 8, colb = flat & 255;
      *(u32x4*)((char*)C + ((size_t)(m0 + row) * Nn + n0) * 2 + colb) =
          *(const u32x4*)(smem + flat);
    }
  } else {
    float* C = (float*)Cout;
    float bj[4];
#pragma unroll
    for (int j = 0; j < 4; ++j) bj[j] = bias[n0 + wc * 64 + j * 16 + l15];
#pragma unroll
    for (int i = 0; i < 4; ++i)
#pragma unroll
      for (int j = 0; j < 4; ++j) {
        int row = m0 + wr * 64 + i * 16 + lhi * 4;
        int col = n0 + wc * 64 + j * 16 + l15;
#pragma unroll
        for (int r = 0; r < 4; ++r) C[(size_t)(row + r) * Nn + col] = acc[i][j][r] + bj[j];
      }
  }
}

// ---------------- RoPE + head reshape for Q,K ----------------
__global__ void k_rope(const bf16* __restrict__ Cq, const float* __restrict__ cs,
                       bf16* __restrict__ Qr, bf16* __restrict__ Kr) {
  int idx = blockIdx.x * 256 + threadIdx.x;  // 2^21
  int i = idx & 31;
  int h = (idx >> 5) & 15;
  int n = (idx >> 9) & 2047;
  int b = idx >> 20;
  const u32* src = (const u32*)(Cq + ((size_t)(b * SEQ + n)) * QKV3);
  float c = cs[((n << 5) + i) * 2], s = cs[((n << 5) + i) * 2 + 1];
  u32 qp = src[h * 32 + i];
  u32 kp = src[512 + h * 32 + i];
  u32 t;
  float q0, q1, kk0, kk1;
  t = qp << 16; __builtin_memcpy(&q0, &t, 4);
  t = qp & 0xffff0000u; __builtin_memcpy(&q1, &t, 4);
  t = kp << 16; __builtin_memcpy(&kk0, &t, 4);
  t = kp & 0xffff0000u; __builtin_memcpy(&kk1, &t, 4);
  bf16 qa = tobf(q0 * c - q1 * s), qb = tobf(q1 * c + q0 * s);
  bf16 ka = tobf(kk0 * c - kk1 * s), kb = tobf(kk1 * c + kk0 * s);
  unsigned short ua, ub;
  __builtin_memcpy(&ua, &qa, 2); __builtin_memcpy(&ub, &qb, 2);
  u32 qo = (u32)ua | ((u32)ub << 16);
  __builtin_memcpy(&ua, &ka, 2); __builtin_memcpy(&ub, &kb, 2);
  u32 ko = (u32)ua | ((u32)ub << 16);
  size_t o32 = ((size_t)(b * NH + h) * SEQ + n) * 32 + i;
  ((u32*)Qr)[o32] = qo;
  ((u32*)Kr)[o32] = ko;
}

// ---------------- V transpose: C_qkv v-part -> V^T [b][h][64][n] ----------------
__global__ void k_vtrans(const bf16* __restrict__ Cq, bf16* __restrict__ Vt) {
  __shared__ __attribute__((aligned(16))) bf16 t[64][72];
  int bid = blockIdx.x;  // b<<9 | h<<5 | nb
  int nb = bid & 31, h = (bid >> 5) & 15, b = bid >> 9;
  int n0 = nb << 6;
  int tid = threadIdx.x;
  int row = tid >> 2, c0 = (tid & 3) << 4;
  const bf16* s = Cq + ((size_t)(b * SEQ + n0 + row)) * QKV3 + 2048 + h * 64 + c0;
  bf16x8 a = *(const bf16x8*)s;
  bf16x8 bv = *(const bf16x8*)(s + 8);
#pragma unroll
  for (int e = 0; e < 8; ++e) { t[row][c0 + e] = a[e]; t[row][c0 + 8 + e] = bv[e]; }
  __syncthreads();
  bf16x8 o0, o1;
#pragma unroll
  for (int e = 0; e < 8; ++e) { o0[e] = t[c0 + e][row]; o1[e] = t[c0 + 8 + e][row]; }
  bf16* d = Vt + ((size_t)((b * NH + h) * 64 + row)) * SEQ + n0 + c0;
  *(bf16x8*)d = o0;
  *(bf16x8*)(d + 8) = o1;
}

// ---------------- Flash attention (split-K, 8 waves) ----------------
// Swapped-operand 32x32 MFMA (lane owns one q). 8 waves/block: waves 0-3 do
// k in [0,1024), waves 4-7 k in [1024,2048) for the SAME 128 q. Fixed
// log2-offset softmax; ssum computed BY THE MATRIX PIPE via a ones-row MFMA
// (acc2 = mfma(ones, P)) -- every output row = sum_k P[k][q], bf16-rounded
// to match PV weights exactly; removes the per-tile unpack+tree + end shfl.
__global__ __launch_bounds__(512, 4) void k_attn(const bf16* __restrict__ Qr,
                                                 const bf16* __restrict__ Kr,
                                                 const bf16* __restrict__ Vt,
                                                 bf16* __restrict__ AO) {
  __shared__ __attribute__((aligned(16))) char lds[2][2][16384];  // [pipe][buf][K 8KB|V 8KB]
  // XCD swizzle: 512 blocks, 8 XCDs -> 64 consecutive works per XCD (4 heads)
  int wg = blockIdx.x;
  int work = (wg & 7) * 64 + (wg >> 3);
  int qc = work & 15, h = (work >> 4) & 15, b = work >> 8;
  int tid = threadIdx.x;
  int wv = tid >> 6, lane = tid & 63;
  int pipe = wv >> 2, wsub = wv & 3;
  int l31 = lane & 31, h5 = lane >> 5;
  int q0 = qc * 128 + wsub * 32;
  int kbase = pipe << 10;  // element offset of this pipe's k-half
  const bf16* Qb = Qr + ((size_t)(b * NH + h)) * SEQ * 64;
  const bf16* Kb = Kr + ((size_t)(b * NH + h)) * SEQ * 64;
  const bf16* Vb = Vt + ((size_t)(b * NH + h)) * 64 * SEQ;

  // staging addresses (2 K insts + 2 V insts per thread per tile; 256 thr/pipe)
  int ptid = tid & 255;
  int sf0 = ptid * 16, sf1 = 4096 + ptid * 16;  // flat byte offsets in 8KB region
  int sr0 = sf0 >> 7, sr1 = sf1 >> 7;
  int sc0 = (sf0 & 127) ^ ((sr0 & 7) << 4);
  int sc1 = (sf1 & 127) ^ ((sr1 & 7) << 4);
  size_t kgb0 = (size_t)sr0 * 64 + (sc0 >> 1), kgb1 = (size_t)sr1 * 64 + (sc1 >> 1);
  size_t vgb0 = (size_t)sr0 * SEQ + (sc0 >> 1), vgb1 = (size_t)sr1 * SEQ + (sc1 >> 1);

#define STAGE(bufp, kb_)                                                                     \
  do {                                                                                       \
    char* bb_ = (bufp);                                                                      \
    size_t ko_ = (size_t)(kbase + (kb_));                                                    \
    __builtin_amdgcn_global_load_lds(GPTR(Kb + ko_ * 64 + kgb0), SPTR(bb_ + sf0), 16, 0, 0); \
    __builtin_amdgcn_global_load_lds(GPTR(Kb + ko_ * 64 + kgb1), SPTR(bb_ + sf1), 16, 0, 0); \
    __builtin_amdgcn_global_load_lds(GPTR(Vb + ko_ + vgb0), SPTR(bb_ + 8192 + sf0), 16, 0, 0); \
    __builtin_amdgcn_global_load_lds(GPTR(Vb + ko_ + vgb1), SPTR(bb_ + 8192 + sf1), 16, 0, 0); \
  } while (0)

  // Q B-frags: col=q=lane&31, k-dim d = s*16 + h5*8 + e
  bf16x8 qf[4];
#pragma unroll
  for (int s = 0; s < 4; ++s) qf[s] = *(const bf16x8*)(Qb + (q0 + l31) * 64 + s * 16 + h5 * 8);

  f32x16 acc0 = {}, acc1 = {}, acc2 = {};
  const float sc = 0.125f * 1.44269504f;  // 1/sqrt(64) * log2(e)
  const float FOFF = 8.0f;                // fixed log2-domain offset (scores bounded)
  const int sw = (l31 & 7) << 4;
  const int cbase = h5 * 16;
  const u32x4 onesw = {0x3F803F80u, 0x3F803F80u, 0x3F803F80u, 0x3F803F80u};
  const bf16x8 onesf = __builtin_bit_cast(bf16x8, onesw);

  STAGE(lds[pipe][0], 0);

  constexpr int NT = (SEQ / 2) / 64;  // 16 tiles per pipe
  for (int t = 0; t < NT; ++t) {
    asm volatile("s_waitcnt vmcnt(0)" ::: "memory");  // this tile's loads landed
    __builtin_amdgcn_s_barrier();  // all waves' parts in LDS; prior-iter reads done
    if (t + 1 < NT) STAGE(lds[pipe][(t + 1) & 1], (t + 1) * 64);
    char* cb = lds[pipe][t & 1];

    // ---- QK^T: S^T[k][q], two 32-k halves ----
    f32x16 st0 = {}, st1 = {};
    __builtin_amdgcn_s_setprio(1);
#pragma unroll
    for (int s = 0; s < 4; ++s) {
      bf16x8 kf0 = *(const bf16x8*)(cb + l31 * 128 + ((s * 32 + cbase) ^ sw));
      bf16x8 kf1 = *(const bf16x8*)(cb + 4096 + l31 * 128 + ((s * 32 + cbase) ^ sw));
      st0 = mfma32(kf0, qf[s], st0);
      st1 = mfma32(kf1, qf[s], st1);
    }
    __builtin_amdgcn_s_setprio(0);

    // ---- softmax numerator, fixed offset (lane owns q=l31) ----
    float p[32];
#pragma unroll
    for (int r = 0; r < 16; ++r) p[r] = __builtin_amdgcn_exp2f(fmaf(st0[r], sc, -FOFF));
#pragma unroll
    for (int r = 0; r < 16; ++r) p[16 + r] = __builtin_amdgcn_exp2f(fmaf(st1[r], sc, -FOFF));

    // ---- pack P to bf16 pairs: P32[i] = pack(p[2i], p[2i+1]) ----
    u32 P32[16];
#pragma unroll
    for (int i = 0; i < 16; ++i) {
      bf16 lo = tobf(p[2 * i]), hi = tobf(p[2 * i + 1]);
      unsigned short ul, uh;
      __builtin_memcpy(&ul, &lo, 2);
      __builtin_memcpy(&uh, &hi, 2);
      P32[i] = (u32)ul | ((u32)uh << 16);
    }

    // half-exchange: send what partner needs (8 shfls)
    const int evens[8] = {0, 1, 4, 5, 8, 9, 12, 13};
    const int odds[8] = {2, 3, 6, 7, 10, 11, 14, 15};
    u32 recv[8];
#pragma unroll
    for (int j = 0; j < 8; ++j) {
      u32 sv = h5 ? P32[evens[j]] : P32[odds[j]];
      recv[j] = (u32)__shfl_xor((int)sv, 32, 64);
    }

    // ---- PV: O^T[d][q] += V^T-frag x P^T-frag; ssum rides the matrix pipe ----
    __builtin_amdgcn_s_setprio(1);
#pragma unroll
    for (int s2 = 0; s2 < 4; ++s2) {
      int x0 = ((s2 >> 1) << 3) + ((s2 & 1) << 2);  // 0,4,8,12
      u32 w0 = h5 ? recv[2 * s2] : P32[x0];
      u32 w1 = h5 ? recv[2 * s2 + 1] : P32[x0 + 1];
      u32 w2 = h5 ? P32[x0 + 2] : recv[2 * s2];
      u32 w3 = h5 ? P32[x0 + 3] : recv[2 * s2 + 1];
      u32x4 wv4 = {w0, w1, w2, w3};
      bf16x8 pfr = __builtin_bit_cast(bf16x8, wv4);
      bf16x8 vf0 = *(const bf16x8*)(cb + 8192 + l31 * 128 + ((s2 * 32 + cbase) ^ sw));
      bf16x8 vf1 = *(const bf16x8*)(cb + 8192 + 4096 + l31 * 128 + ((s2 * 32 + cbase) ^ sw));
      acc0 = mfma32(vf0, pfr, acc0);
      acc1 = mfma32(vf1, pfr, acc1);
      acc2 = mfma32(onesf, pfr, acc2);  // row r of ones*P = sum_k P[k][q], all rows equal
    }
    __builtin_amdgcn_s_setprio(0);
  }
  float ssum = acc2[0];  // per-lane q sum over this pipe's full k-half

  // ---- split-K merge: pipe1 -> LDS -> pipe0 adds; then normalize+store ----
  __syncthreads();  // all staging reads done; LDS reusable
  float* cacc = (float*)&lds[0][0][0];                  // [4][64][36] padded
  float* csum = (float*)(&lds[0][0][0] + 36864);        // [4][64]
  int slot = (wsub * 64 + lane) * 36;
  if (pipe == 1) {
#pragma unroll
    for (int r = 0; r < 16; r += 4) {
      *(f32x4*)(cacc + slot + r) = f32x4{acc0[r], acc0[r + 1], acc0[r + 2], acc0[r + 3]};
      *(f32x4*)(cacc + slot + 16 + r) = f32x4{acc1[r], acc1[r + 1], acc1[r + 2], acc1[r + 3]};
    }
    csum[wsub * 64 + lane] = ssum;
  }
  __syncthreads();
  if (pipe == 0) {
#pragma unroll
    for (int r = 0; r < 16; r += 4) {
      f32x4 v0 = *(const f32x4*)(cacc + slot + r);
      f32x4 v1 = *(const f32x4*)(cacc + slot + 16 + r);
#pragma unroll
      for (int j = 0; j < 4; ++j) { acc0[r + j] += v0[j]; acc1[r + j] += v1[j]; }
    }
    ssum += csum[wsub * 64 + lane];
    float inv = 1.0f / ssum;
    size_t tok = (size_t)(b * SEQ + q0 + l31);
#pragma unroll
    for (int a = 0; a < 4; ++a) {
      bf16x4 ov0, ov1;
#pragma unroll
      for (int j = 0; j < 4; ++j) {
        ov0[j] = tobf(acc0[4 * a + j] * inv);
        ov1[j] = tobf(acc1[4 * a + j] * inv);
      }
      *(bf16x4*)(AO + tok * (NH * HD) + h * 64 + 8 * a + 4 * h5) = ov0;
      *(bf16x4*)(AO + tok * (NH * HD) + h * 64 + 32 + 8 * a + 4 * h5) = ov1;
    }
  }
#undef STAGE
}

// ---------------- launcher ----------------

extern "C" void kernel_launch(void* const* d_in, const int* in_sizes, int n_in,
                              void* d_out, int out_size, void* d_ws, size_t ws_size,
                              hipStream_t stream) {
  const float* hs = (const float*)d_in[0];
  const float* wqkv = (const float*)d_in[1];
  const float* wout = (const float*)d_in[2];
  const float* bout = (const float*)d_in[3];
  char* ws = (char*)d_ws;
  bf16* Xb = (bf16*)(ws + OXB);
  bf16* Wqkt = (bf16*)(ws + OWQ);
  bf16* Woutt = (bf16*)(ws + OWO);
  float* cs = (float*)(ws + OCS);
  bf16* Cqkv = (bf16*)(ws + OCQ);
  bf16* Qr = (bf16*)(ws + OQR);
  bf16* Kr = (bf16*)(ws + OKR);
  bf16* Vt = (bf16*)(ws + OVT);
  bf16* AO = (bf16*)(ws + OAO);

  k_costab<<<256, 256, 0, stream>>>(cs);
  k_cvt<<<(MTOK * DMODEL / 4 + 255) / 256, 256, 0, stream>>>(hs, Xb, MTOK * DMODEL / 4);
  k_trans<<<dim3(QKV3 / 32, DMODEL / 32), 256, 0, stream>>>(wqkv, Wqkt, DMODEL, QKV3);
  k_trans<<<dim3(DMODEL / 32, DMODEL / 32), 256, 0, stream>>>(wout, Woutt, DMODEL, DMODEL);
  k_gemm<1><<<(MTOK / 128) * (QKV3 / 128), 256, 0, stream>>>(Xb, Wqkt, Cqkv, nullptr, MTOK, QKV3, DMODEL);
  k_rope<<<(BATCH * SEQ * NH * 32) / 256, 256, 0, stream>>>(Cqkv, cs, Qr, Kr);
  k_vtrans<<<BATCH * NH * (SEQ / 64), 256, 0, stream>>>(Cqkv, Vt);
  k_attn<<<BATCH * NH * (SEQ / 128), 512, 0, stream>>>(Qr, Kr, Vt, AO);
  k_gemm<0><<<(MTOK / 128) * (DMODEL / 128), 256, 0, stream>>>(AO, Woutt, d_out, bout, MTOK, DMODEL, DMODEL);
}

// Round 8
// 162.063 us; speedup vs baseline: 1.3496x; 1.3496x over previous
//
#include <hip/hip_runtime.h>
#include <hip/hip_bf16.h>

typedef __bf16 bf16;
typedef unsigned int u32;
typedef __attribute__((ext_vector_type(4))) float f32x4;
typedef __attribute__((ext_vector_type(16))) float f32x16;
typedef __attribute__((ext_vector_type(8))) bf16 bf16x8;
typedef __attribute__((ext_vector_type(4))) bf16 bf16x4;
typedef __attribute__((ext_vector_type(4))) u32 u32x4;

#define GPTR(p) ((const __attribute__((address_space(1))) u32*)(p))
#define SPTR(p) ((__attribute__((address_space(3))) u32*)(p))

// Problem constants
constexpr int BATCH = 2, SEQ = 2048, DMODEL = 1024, NH = 16, HD = 64, QKV3 = 3072;
constexpr int MTOK = BATCH * SEQ;  // 4096 tokens

// Workspace layout (bytes)
constexpr size_t OXB = 0;                                       // X bf16 [4096][1024]
constexpr size_t OWQ = OXB + (size_t)MTOK * DMODEL * 2;         // Wqkv^T bf16 [3072][1024]
constexpr size_t OWO = OWQ + (size_t)QKV3 * DMODEL * 2;         // Wout^T bf16 [1024][1024]
constexpr size_t OCS = OWO + (size_t)DMODEL * DMODEL * 2;       // cos/sin f32 [2048][32][2]
constexpr size_t OCQ = OCS + (size_t)SEQ * 32 * 8;              // C_qkv bf16 [4096][3072]
constexpr size_t OQR = OCQ + (size_t)MTOK * QKV3 * 2;           // Q roped [b][h][n][64]
constexpr size_t OKR = OQR + (size_t)BATCH * NH * SEQ * HD * 2; // K roped
constexpr size_t OVT = OKR + (size_t)BATCH * NH * SEQ * HD * 2; // V^T [b][h][64][n]
constexpr size_t OAO = OXB;                                     // attn out (aliases Xb, dead by then)

static __device__ __forceinline__ bf16 tobf(float x) { return (bf16)x; }
static __device__ __forceinline__ float tof(bf16 x) { return (float)x; }

static __device__ __forceinline__ f32x4 mfma16(bf16x8 a, bf16x8 b, f32x4 c) {
  return __builtin_amdgcn_mfma_f32_16x16x32_bf16(a, b, c, 0, 0, 0);
}
static __device__ __forceinline__ f32x16 mfma32(bf16x8 a, bf16x8 b, f32x16 c) {
  return __builtin_amdgcn_mfma_f32_32x32x16_bf16(a, b, c, 0, 0, 0);
}

// ---------------- prep kernels ----------------

__global__ void k_costab(float* __restrict__ cs) {
  int idx = blockIdx.x * 256 + threadIdx.x;  // 65536 = 2048*32
  int n = idx >> 5, i = idx & 31;
  float freq = powf(10000.0f, -(float)(2 * i) / 64.0f);
  float ang = (float)n * freq;
  float s, c;
  sincosf(ang, &s, &c);
  cs[idx * 2] = c;
  cs[idx * 2 + 1] = s;
}

__global__ void k_cvt(const float* __restrict__ x, bf16* __restrict__ y, int n4) {
  int i = blockIdx.x * 256 + threadIdx.x;
  if (i >= n4) return;
  float4 v = ((const float4*)x)[i];
  bf16x4 o = {tobf(v.x), tobf(v.y), tobf(v.z), tobf(v.w)};
  ((bf16x4*)y)[i] = o;
}

// transpose-convert: in f32 [R][C] -> out bf16 [C][R]
__global__ void k_trans(const float* __restrict__ in, bf16* __restrict__ out, int R, int C) {
  __shared__ float tile[32][33];
  int k0 = blockIdx.y * 32, n0 = blockIdx.x * 32;
  int tx = threadIdx.x & 31, ty = threadIdx.x >> 5;  // ty 0..7
#pragma unroll
  for (int r = ty; r < 32; r += 8) tile[r][tx] = in[(size_t)(k0 + r) * C + n0 + tx];
  __syncthreads();
#pragma unroll
  for (int r = ty; r < 32; r += 8) out[(size_t)(n0 + r) * R + k0 + tx] = tobf(tile[tx][r]);
}

// ---------------- GEMM: A bf16 [M][K] x Bt bf16 [N][K] -> C ----------------
// 128x128 tile, BK=32, double-buffered LDS, 2-phase loop: one barrier/iter,
// staging loads for t+1 fly under tile t's ds_read+MFMA. XCD-swizzled grid.

template <int BF16OUT>
__global__ __launch_bounds__(256) void k_gemm(const bf16* __restrict__ A, const bf16* __restrict__ Bt,
                                              void* __restrict__ Cout, const float* __restrict__ bias,
                                              int M, int Nn, int K) {
  __shared__ __attribute__((aligned(16))) char smem[32768];  // 2 x (As 8KB | Bs 8KB)
  const int nTn = Nn >> 7;
  int nwg = gridDim.x;
  int bid = blockIdx.x;
  int wgs = (bid & 7) * (nwg >> 3) + (bid >> 3);  // bijective XCD swizzle (nwg%8==0)
  const int m0 = (wgs / nTn) << 7;
  const int n0 = (wgs % nTn) << 7;
  const int tid = threadIdx.x;
  const int lane = tid & 63, w = tid >> 6;
  const int wr = w >> 1, wc = w & 1;
  const int l15 = lane & 15, lhi = lane >> 4;
  f32x4 acc[4][4] = {};

  const int flat0 = w * 1024 + lane * 16;  // byte offset in 8KB half-tile
  const int flat1 = flat0 + 4096;
  const int row0 = flat0 >> 6, ke0 = (flat0 & 63) >> 1;
  const int row1 = flat1 >> 6, ke1 = (flat1 & 63) >> 1;

#define GSTAGE(bb_, k0_)                                                                       \
  do {                                                                                         \
    __builtin_amdgcn_global_load_lds(GPTR(A + (size_t)(m0 + row0) * K + (k0_) + ke0),          \
                                     SPTR(smem + (bb_)*16384 + flat0), 16, 0, 0);              \
    __builtin_amdgcn_global_load_lds(GPTR(A + (size_t)(m0 + row1) * K + (k0_) + ke1),          \
                                     SPTR(smem + (bb_)*16384 + flat1), 16, 0, 0);              \
    __builtin_amdgcn_global_load_lds(GPTR(Bt + (size_t)(n0 + row0) * K + (k0_) + ke0),         \
                                     SPTR(smem + (bb_)*16384 + 8192 + flat0), 16, 0, 0);       \
    __builtin_amdgcn_global_load_lds(GPTR(Bt + (size_t)(n0 + row1) * K + (k0_) + ke1),         \
                                     SPTR(smem + (bb_)*16384 + 8192 + flat1), 16, 0, 0);       \
  } while (0)

  GSTAGE(0, 0);
  const int nIt = K >> 5;
  for (int it = 0; it < nIt; ++it) {
    asm volatile("s_waitcnt vmcnt(0)" ::: "memory");  // tile it staged
    __builtin_amdgcn_s_barrier();                     // prev reads done; tile it visible
    if (it + 1 < nIt) GSTAGE((it + 1) & 1, (it + 1) << 5);
    const bf16* As = (const bf16*)(smem + (it & 1) * 16384);
    const bf16* Bs = (const bf16*)(smem + (it & 1) * 16384 + 8192);
    bf16x8 af[4], bfv[4];
#pragma unroll
    for (int i = 0; i < 4; ++i) {
      af[i] = *(const bf16x8*)(As + (wr * 64 + i * 16 + l15) * 32 + lhi * 8);
      bfv[i] = *(const bf16x8*)(Bs + (wc * 64 + i * 16 + l15) * 32 + lhi * 8);
    }
    __builtin_amdgcn_s_setprio(1);
#pragma unroll
    for (int i = 0; i < 4; ++i)
#pragma unroll
      for (int j = 0; j < 4; ++j) acc[i][j] = mfma16(af[i], bfv[j], acc[i][j]);
    __builtin_amdgcn_s_setprio(0);
  }
#undef GSTAGE

  if constexpr (BF16OUT) {
    __syncthreads();  // all waves done with last tile's LDS before overlay
    bf16* Cs = (bf16*)smem;  // [128][128]
#pragma unroll
    for (int i = 0; i < 4; ++i)
#pragma unroll
      for (int j = 0; j < 4; ++j) {
        int row = wr * 64 + i * 16 + lhi * 4;
        int col = wc * 64 + j * 16 + l15;
#pragma unroll
        for (int r = 0; r < 4; ++r) Cs[(row + r) * 128 + col] = tobf(acc[i][j][r]);
      }
    __syncthreads();
    bf16* C = (bf16*)Cout;
#pragma unroll
    for (int inst = 0; inst < 8; ++inst) {
      int flat = inst * 4096 + tid * 16;  // bytes over 32KB
      int row = flat >> 8, colb = flat & 255;
      *(u32x4*)((char*)C + ((size_t)(m0 + row) * Nn + n0) * 2 + colb) =
          *(const u32x4*)(smem + flat);
    }
  } else {
    float* C = (float*)Cout;
    float bj[4];
#pragma unroll
    for (int j = 0; j < 4; ++j) bj[j] = bias[n0 + wc * 64 + j * 16 + l15];
#pragma unroll
    for (int i = 0; i < 4; ++i)
#pragma unroll
      for (int j = 0; j < 4; ++j) {
        int row = m0 + wr * 64 + i * 16 + lhi * 4;
        int col = n0 + wc * 64 + j * 16 + l15;
#pragma unroll
        for (int r = 0; r < 4; ++r) C[(size_t)(row + r) * Nn + col] = acc[i][j][r] + bj[j];
      }
  }
}

// ---------------- RoPE + head reshape for Q,K ----------------
__global__ void k_rope(const bf16* __restrict__ Cq, const float* __restrict__ cs,
                       bf16* __restrict__ Qr, bf16* __restrict__ Kr) {
  int idx = blockIdx.x * 256 + threadIdx.x;  // 2^21
  int i = idx & 31;
  int h = (idx >> 5) & 15;
  int n = (idx >> 9) & 2047;
  int b = idx >> 20;
  const u32* src = (const u32*)(Cq + ((size_t)(b * SEQ + n)) * QKV3);
  float c = cs[((n << 5) + i) * 2], s = cs[((n << 5) + i) * 2 + 1];
  u32 qp = src[h * 32 + i];
  u32 kp = src[512 + h * 32 + i];
  u32 t;
  float q0, q1, kk0, kk1;
  t = qp << 16; __builtin_memcpy(&q0, &t, 4);
  t = qp & 0xffff0000u; __builtin_memcpy(&q1, &t, 4);
  t = kp << 16; __builtin_memcpy(&kk0, &t, 4);
  t = kp & 0xffff0000u; __builtin_memcpy(&kk1, &t, 4);
  bf16 qa = tobf(q0 * c - q1 * s), qb = tobf(q1 * c + q0 * s);
  bf16 ka = tobf(kk0 * c - kk1 * s), kb = tobf(kk1 * c + kk0 * s);
  unsigned short ua, ub;
  __builtin_memcpy(&ua, &qa, 2); __builtin_memcpy(&ub, &qb, 2);
  u32 qo = (u32)ua | ((u32)ub << 16);
  __builtin_memcpy(&ua, &ka, 2); __builtin_memcpy(&ub, &kb, 2);
  u32 ko = (u32)ua | ((u32)ub << 16);
  size_t o32 = ((size_t)(b * NH + h) * SEQ + n) * 32 + i;
  ((u32*)Qr)[o32] = qo;
  ((u32*)Kr)[o32] = ko;
}

// ---------------- V transpose: C_qkv v-part -> V^T [b][h][64][n] ----------------
__global__ void k_vtrans(const bf16* __restrict__ Cq, bf16* __restrict__ Vt) {
  __shared__ __attribute__((aligned(16))) bf16 t[64][72];
  int bid = blockIdx.x;  // b<<9 | h<<5 | nb
  int nb = bid & 31, h = (bid >> 5) & 15, b = bid >> 9;
  int n0 = nb << 6;
  int tid = threadIdx.x;
  int row = tid >> 2, c0 = (tid & 3) << 4;
  const bf16* s = Cq + ((size_t)(b * SEQ + n0 + row)) * QKV3 + 2048 + h * 64 + c0;
  bf16x8 a = *(const bf16x8*)s;
  bf16x8 bv = *(const bf16x8*)(s + 8);
#pragma unroll
  for (int e = 0; e < 8; ++e) { t[row][c0 + e] = a[e]; t[row][c0 + 8 + e] = bv[e]; }
  __syncthreads();
  bf16x8 o0, o1;
#pragma unroll
  for (int e = 0; e < 8; ++e) { o0[e] = t[c0 + e][row]; o1[e] = t[c0 + 8 + e][row]; }
  bf16* d = Vt + ((size_t)((b * NH + h) * 64 + row)) * SEQ + n0 + c0;
  *(bf16x8*)d = o0;
  *(bf16x8*)(d + 8) = o1;
}

// ---------------- Flash attention (split-K, 8 waves) ----------------
// Round-6 proven structure: swapped-operand 32x32 MFMA (lane owns one q);
// 8 waves/block split-K (waves 0-3: k in [0,1024), waves 4-7: [1024,2048));
// two 2-buffer global_load_lds pipelines, one barrier/iter; XOR-swizzled LDS;
// fixed log2-offset softmax; ssum via VALU tree over bf16-ROUNDED P (matches
// PV weights exactly). NO ones-MFMA ssum: +16 acc VGPRs caused scratch spill
// in the k-loop (r7: FETCH 215MB, WRITE 300MB, attn 152us).
__global__ __launch_bounds__(512, 4) void k_attn(const bf16* __restrict__ Qr,
                                                 const bf16* __restrict__ Kr,
                                                 const bf16* __restrict__ Vt,
                                                 bf16* __restrict__ AO) {
  __shared__ __attribute__((aligned(16))) char lds[2][2][16384];  // [pipe][buf][K 8KB|V 8KB]
  // XCD swizzle: 512 blocks, 8 XCDs -> 64 consecutive works per XCD (4 heads)
  int wg = blockIdx.x;
  int work = (wg & 7) * 64 + (wg >> 3);
  int qc = work & 15, h = (work >> 4) & 15, b = work >> 8;
  int tid = threadIdx.x;
  int wv = tid >> 6, lane = tid & 63;
  int pipe = wv >> 2, wsub = wv & 3;
  int l31 = lane & 31, h5 = lane >> 5;
  int q0 = qc * 128 + wsub * 32;
  int kbase = pipe << 10;  // element offset of this pipe's k-half
  const bf16* Qb = Qr + ((size_t)(b * NH + h)) * SEQ * 64;
  const bf16* Kb = Kr + ((size_t)(b * NH + h)) * SEQ * 64;
  const bf16* Vb = Vt + ((size_t)(b * NH + h)) * 64 * SEQ;

  // staging addresses (2 K insts + 2 V insts per thread per tile; 256 thr/pipe)
  int ptid = tid & 255;
  int sf0 = ptid * 16, sf1 = 4096 + ptid * 16;  // flat byte offsets in 8KB region
  int sr0 = sf0 >> 7, sr1 = sf1 >> 7;
  int sc0 = (sf0 & 127) ^ ((sr0 & 7) << 4);
  int sc1 = (sf1 & 127) ^ ((sr1 & 7) << 4);
  size_t kgb0 = (size_t)sr0 * 64 + (sc0 >> 1), kgb1 = (size_t)sr1 * 64 + (sc1 >> 1);
  size_t vgb0 = (size_t)sr0 * SEQ + (sc0 >> 1), vgb1 = (size_t)sr1 * SEQ + (sc1 >> 1);

#define STAGE(bufp, kb_)                                                                     \
  do {                                                                                       \
    char* bb_ = (bufp);                                                                      \
    size_t ko_ = (size_t)(kbase + (kb_));                                                    \
    __builtin_amdgcn_global_load_lds(GPTR(Kb + ko_ * 64 + kgb0), SPTR(bb_ + sf0), 16, 0, 0); \
    __builtin_amdgcn_global_load_lds(GPTR(Kb + ko_ * 64 + kgb1), SPTR(bb_ + sf1), 16, 0, 0); \
    __builtin_amdgcn_global_load_lds(GPTR(Vb + ko_ + vgb0), SPTR(bb_ + 8192 + sf0), 16, 0, 0); \
    __builtin_amdgcn_global_load_lds(GPTR(Vb + ko_ + vgb1), SPTR(bb_ + 8192 + sf1), 16, 0, 0); \
  } while (0)

  // Q B-frags: col=q=lane&31, k-dim d = s*16 + h5*8 + e
  bf16x8 qf[4];
#pragma unroll
  for (int s = 0; s < 4; ++s) qf[s] = *(const bf16x8*)(Qb + (q0 + l31) * 64 + s * 16 + h5 * 8);

  f32x16 acc0 = {}, acc1 = {};
  float ssum = 0.f;
  const float sc = 0.125f * 1.44269504f;  // 1/sqrt(64) * log2(e)
  const float FOFF = 8.0f;                // fixed log2-domain offset (scores bounded)
  const int sw = (l31 & 7) << 4;
  const int cbase = h5 * 16;

  STAGE(lds[pipe][0], 0);

  constexpr int NT = (SEQ / 2) / 64;  // 16 tiles per pipe
  for (int t = 0; t < NT; ++t) {
    asm volatile("s_waitcnt vmcnt(0)" ::: "memory");  // this tile's loads landed
    __builtin_amdgcn_s_barrier();  // all waves' parts in LDS; prior-iter reads done
    if (t + 1 < NT) STAGE(lds[pipe][(t + 1) & 1], (t + 1) * 64);
    char* cb = lds[pipe][t & 1];

    // ---- QK^T: S^T[k][q], two 32-k halves ----
    f32x16 st0 = {}, st1 = {};
    __builtin_amdgcn_s_setprio(1);
#pragma unroll
    for (int s = 0; s < 4; ++s) {
      bf16x8 kf0 = *(const bf16x8*)(cb + l31 * 128 + ((s * 32 + cbase) ^ sw));
      bf16x8 kf1 = *(const bf16x8*)(cb + 4096 + l31 * 128 + ((s * 32 + cbase) ^ sw));
      st0 = mfma32(kf0, qf[s], st0);
      st1 = mfma32(kf1, qf[s], st1);
    }
    __builtin_amdgcn_s_setprio(0);

    // ---- softmax numerator, fixed offset (lane owns q=l31) ----
    float p[32];
#pragma unroll
    for (int r = 0; r < 16; ++r) p[r] = __builtin_amdgcn_exp2f(fmaf(st0[r], sc, -FOFF));
#pragma unroll
    for (int r = 0; r < 16; ++r) p[16 + r] = __builtin_amdgcn_exp2f(fmaf(st1[r], sc, -FOFF));

    // ---- pack P to bf16 pairs: P32[i] = pack(p[2i], p[2i+1]) ----
    u32 P32[16];
#pragma unroll
    for (int i = 0; i < 16; ++i) {
      bf16 lo = tobf(p[2 * i]), hi = tobf(p[2 * i + 1]);
      unsigned short ul, uh;
      __builtin_memcpy(&ul, &lo, 2);
      __builtin_memcpy(&uh, &hi, 2);
      P32[i] = (u32)ul | ((u32)uh << 16);
    }
    // ssum from the bf16-ROUNDED values (normalization matches PV weights)
    float sm[16];
#pragma unroll
    for (int i = 0; i < 16; ++i) {
      u32 ulo = P32[i] << 16, uhi = P32[i] & 0xffff0000u;
      float flo, fhi;
      __builtin_memcpy(&flo, &ulo, 4);
      __builtin_memcpy(&fhi, &uhi, 4);
      sm[i] = flo + fhi;
    }
#pragma unroll
    for (int off = 8; off > 0; off >>= 1)
#pragma unroll
      for (int r = 0; r < off; ++r) sm[r] += sm[r + off];
    ssum += sm[0];

    // half-exchange: send what partner needs (8 shfls)
    const int evens[8] = {0, 1, 4, 5, 8, 9, 12, 13};
    const int odds[8] = {2, 3, 6, 7, 10, 11, 14, 15};
    u32 recv[8];
#pragma unroll
    for (int j = 0; j < 8; ++j) {
      u32 sv = h5 ? P32[evens[j]] : P32[odds[j]];
      recv[j] = (u32)__shfl_xor((int)sv, 32, 64);
    }

    // ---- PV: O^T[d][q] += V^T-frag x P^T-frag ----
    __builtin_amdgcn_s_setprio(1);
#pragma unroll
    for (int s2 = 0; s2 < 4; ++s2) {
      int x0 = ((s2 >> 1) << 3) + ((s2 & 1) << 2);  // 0,4,8,12
      u32 w0 = h5 ? recv[2 * s2] : P32[x0];
      u32 w1 = h5 ? recv[2 * s2 + 1] : P32[x0 + 1];
      u32 w2 = h5 ? P32[x0 + 2] : recv[2 * s2];
      u32 w3 = h5 ? P32[x0 + 3] : recv[2 * s2 + 1];
      u32x4 wv4 = {w0, w1, w2, w3};
      bf16x8 pfr = __builtin_bit_cast(bf16x8, wv4);
      bf16x8 vf0 = *(const bf16x8*)(cb + 8192 + l31 * 128 + ((s2 * 32 + cbase) ^ sw));
      bf16x8 vf1 = *(const bf16x8*)(cb + 8192 + 4096 + l31 * 128 + ((s2 * 32 + cbase) ^ sw));
      acc0 = mfma32(vf0, pfr, acc0);
      acc1 = mfma32(vf1, pfr, acc1);
    }
    __builtin_amdgcn_s_setprio(0);
  }

  // ---- split-K merge: pipe1 -> LDS -> pipe0 adds; then normalize+store ----
  __syncthreads();  // all staging reads done; LDS reusable
  float* cacc = (float*)&lds[0][0][0];                  // [4][64][36] padded
  float* csum = (float*)(&lds[0][0][0] + 36864);        // [4][64]
  int slot = (wsub * 64 + lane) * 36;
  if (pipe == 1) {
#pragma unroll
    for (int r = 0; r < 16; r += 4) {
      *(f32x4*)(cacc + slot + r) = f32x4{acc0[r], acc0[r + 1], acc0[r + 2], acc0[r + 3]};
      *(f32x4*)(cacc + slot + 16 + r) = f32x4{acc1[r], acc1[r + 1], acc1[r + 2], acc1[r + 3]};
    }
    csum[wsub * 64 + lane] = ssum;
  }
  __syncthreads();
  if (pipe == 0) {
#pragma unroll
    for (int r = 0; r < 16; r += 4) {
      f32x4 v0 = *(const f32x4*)(cacc + slot + r);
      f32x4 v1 = *(const f32x4*)(cacc + slot + 16 + r);
#pragma unroll
      for (int j = 0; j < 4; ++j) { acc0[r + j] += v0[j]; acc1[r + j] += v1[j]; }
    }
    ssum += csum[wsub * 64 + lane];
    ssum += __shfl_xor(ssum, 32, 64);
    float inv = 1.0f / ssum;
    size_t tok = (size_t)(b * SEQ + q0 + l31);
#pragma unroll
    for (int a = 0; a < 4; ++a) {
      bf16x4 ov0, ov1;
#pragma unroll
      for (int j = 0; j < 4; ++j) {
        ov0[j] = tobf(acc0[4 * a + j] * inv);
        ov1[j] = tobf(acc1[4 * a + j] * inv);
      }
      *(bf16x4*)(AO + tok * (NH * HD) + h * 64 + 8 * a + 4 * h5) = ov0;
      *(bf16x4*)(AO + tok * (NH * HD) + h * 64 + 32 + 8 * a + 4 * h5) = ov1;
    }
  }
#undef STAGE
}

// ---------------- launcher ----------------

extern "C" void kernel_launch(void* const* d_in, const int* in_sizes, int n_in,
                              void* d_out, int out_size, void* d_ws, size_t ws_size,
                              hipStream_t stream) {
  const float* hs = (const float*)d_in[0];
  const float* wqkv = (const float*)d_in[1];
  const float* wout = (const float*)d_in[2];
  const float* bout = (const float*)d_in[3];
  char* ws = (char*)d_ws;
  bf16* Xb = (bf16*)(ws + OXB);
  bf16* Wqkt = (bf16*)(ws + OWQ);
  bf16* Woutt = (bf16*)(ws + OWO);
  float* cs = (float*)(ws + OCS);
  bf16* Cqkv = (bf16*)(ws + OCQ);
  bf16* Qr = (bf16*)(ws + OQR);
  bf16* Kr = (bf16*)(ws + OKR);
  bf16* Vt = (bf16*)(ws + OVT);
  bf16* AO = (bf16*)(ws + OAO);

  k_costab<<<256, 256, 0, stream>>>(cs);
  k_cvt<<<(MTOK * DMODEL / 4 + 255) / 256, 256, 0, stream>>>(hs, Xb, MTOK * DMODEL / 4);
  k_trans<<<dim3(QKV3 / 32, DMODEL / 32), 256, 0, stream>>>(wqkv, Wqkt, DMODEL, QKV3);
  k_trans<<<dim3(DMODEL / 32, DMODEL / 32), 256, 0, stream>>>(wout, Woutt, DMODEL, DMODEL);
  k_gemm<1><<<(MTOK / 128) * (QKV3 / 128), 256, 0, stream>>>(Xb, Wqkt, Cqkv, nullptr, MTOK, QKV3, DMODEL);
  k_rope<<<(BATCH * SEQ * NH * 32) / 256, 256, 0, stream>>>(Cqkv, cs, Qr, Kr);
  k_vtrans<<<BATCH * NH * (SEQ / 64), 256, 0, stream>>>(Cqkv, Vt);
  k_attn<<<BATCH * NH * (SEQ / 128), 512, 0, stream>>>(Qr, Kr, Vt, AO);
  k_gemm<0><<<(MTOK / 128) * (DMODEL / 128), 256, 0, stream>>>(AO, Woutt, d_out, bout, MTOK, DMODEL, DMODEL);
}

// Round 9
// 157.964 us; speedup vs baseline: 1.3846x; 1.0259x over previous
//
#include <hip/hip_runtime.h>
#include <hip/hip_bf16.h>

typedef __bf16 bf16;
typedef unsigned int u32;
typedef __attribute__((ext_vector_type(4))) float f32x4;
typedef __attribute__((ext_vector_type(16))) float f32x16;
typedef __attribute__((ext_vector_type(8))) bf16 bf16x8;
typedef __attribute__((ext_vector_type(4))) bf16 bf16x4;
typedef __attribute__((ext_vector_type(4))) u32 u32x4;

#define GPTR(p) ((const __attribute__((address_space(1))) u32*)(p))
#define SPTR(p) ((__attribute__((address_space(3))) u32*)(p))

// Problem constants
constexpr int BATCH = 2, SEQ = 2048, DMODEL = 1024, NH = 16, HD = 64, QKV3 = 3072;
constexpr int MTOK = BATCH * SEQ;  // 4096 tokens

// Workspace layout (bytes)
constexpr size_t OXB = 0;                                       // X bf16 [4096][1024]
constexpr size_t OWQ = OXB + (size_t)MTOK * DMODEL * 2;         // Wqkv^T bf16 [3072][1024]
constexpr size_t OWO = OWQ + (size_t)QKV3 * DMODEL * 2;         // Wout^T bf16 [1024][1024]
constexpr size_t OCS = OWO + (size_t)DMODEL * DMODEL * 2;       // cos/sin f32 [2048][32][2]
constexpr size_t OCQ = OCS + (size_t)SEQ * 32 * 8;              // C_qkv bf16 [4096][3072]
constexpr size_t OQR = OCQ + (size_t)MTOK * QKV3 * 2;           // Q roped [b][h][n][64]
constexpr size_t OKR = OQR + (size_t)BATCH * NH * SEQ * HD * 2; // K roped
constexpr size_t OVT = OKR + (size_t)BATCH * NH * SEQ * HD * 2; // V^T [b][h][64][n]
constexpr size_t OAO = OXB;                                     // attn out (aliases Xb, dead by then)

static __device__ __forceinline__ bf16 tobf(float x) { return (bf16)x; }
static __device__ __forceinline__ float tof(bf16 x) { return (float)x; }

static __device__ __forceinline__ f32x4 mfma16(bf16x8 a, bf16x8 b, f32x4 c) {
  return __builtin_amdgcn_mfma_f32_16x16x32_bf16(a, b, c, 0, 0, 0);
}
static __device__ __forceinline__ f32x16 mfma32(bf16x8 a, bf16x8 b, f32x16 c) {
  return __builtin_amdgcn_mfma_f32_32x32x16_bf16(a, b, c, 0, 0, 0);
}

// ---------------- prep kernels ----------------

__global__ void k_costab(float* __restrict__ cs) {
  int idx = blockIdx.x * 256 + threadIdx.x;  // 65536 = 2048*32
  int n = idx >> 5, i = idx & 31;
  float freq = powf(10000.0f, -(float)(2 * i) / 64.0f);
  float ang = (float)n * freq;
  float s, c;
  sincosf(ang, &s, &c);
  cs[idx * 2] = c;
  cs[idx * 2 + 1] = s;
}

__global__ void k_cvt(const float* __restrict__ x, bf16* __restrict__ y, int n4) {
  int i = blockIdx.x * 256 + threadIdx.x;
  if (i >= n4) return;
  float4 v = ((const float4*)x)[i];
  bf16x4 o = {tobf(v.x), tobf(v.y), tobf(v.z), tobf(v.w)};
  ((bf16x4*)y)[i] = o;
}

// transpose-convert: in f32 [R][C] -> out bf16 [C][R]
__global__ void k_trans(const float* __restrict__ in, bf16* __restrict__ out, int R, int C) {
  __shared__ float tile[32][33];
  int k0 = blockIdx.y * 32, n0 = blockIdx.x * 32;
  int tx = threadIdx.x & 31, ty = threadIdx.x >> 5;  // ty 0..7
#pragma unroll
  for (int r = ty; r < 32; r += 8) tile[r][tx] = in[(size_t)(k0 + r) * C + n0 + tx];
  __syncthreads();
#pragma unroll
  for (int r = ty; r < 32; r += 8) out[(size_t)(n0 + r) * R + k0 + tx] = tobf(tile[tx][r]);
}

// ---------------- GEMM: A bf16 [M][K] x Bt bf16 [N][K] -> C ----------------
// 128x128 tile, BK=32, THREE-buffer LDS, counted vmcnt(4): tile t+1's loads
// stay in flight across the barrier (T4). One barrier/iter. XCD-swizzled grid.

template <int BF16OUT>
__global__ __launch_bounds__(256) void k_gemm(const bf16* __restrict__ A, const bf16* __restrict__ Bt,
                                              void* __restrict__ Cout, const float* __restrict__ bias,
                                              int M, int Nn, int K) {
  __shared__ __attribute__((aligned(16))) char smem[49152];  // 3 x (As 8KB | Bs 8KB)
  const int nTn = Nn >> 7;
  int nwg = gridDim.x;
  int bid = blockIdx.x;
  int wgs = (bid & 7) * (nwg >> 3) + (bid >> 3);  // bijective XCD swizzle (nwg%8==0)
  const int m0 = (wgs / nTn) << 7;
  const int n0 = (wgs % nTn) << 7;
  const int tid = threadIdx.x;
  const int lane = tid & 63, w = tid >> 6;
  const int wr = w >> 1, wc = w & 1;
  const int l15 = lane & 15, lhi = lane >> 4;
  f32x4 acc[4][4] = {};

  const int flat0 = w * 1024 + lane * 16;  // byte offset in 8KB half-tile
  const int flat1 = flat0 + 4096;
  const int row0 = flat0 >> 6, ke0 = (flat0 & 63) >> 1;
  const int row1 = flat1 >> 6, ke1 = (flat1 & 63) >> 1;

#define GSTAGE(bb_, k0_)                                                                       \
  do {                                                                                         \
    __builtin_amdgcn_global_load_lds(GPTR(A + (size_t)(m0 + row0) * K + (k0_) + ke0),          \
                                     SPTR(smem + (bb_)*16384 + flat0), 16, 0, 0);              \
    __builtin_amdgcn_global_load_lds(GPTR(A + (size_t)(m0 + row1) * K + (k0_) + ke1),          \
                                     SPTR(smem + (bb_)*16384 + flat1), 16, 0, 0);              \
    __builtin_amdgcn_global_load_lds(GPTR(Bt + (size_t)(n0 + row0) * K + (k0_) + ke0),         \
                                     SPTR(smem + (bb_)*16384 + 8192 + flat0), 16, 0, 0);       \
    __builtin_amdgcn_global_load_lds(GPTR(Bt + (size_t)(n0 + row1) * K + (k0_) + ke1),         \
                                     SPTR(smem + (bb_)*16384 + 8192 + flat1), 16, 0, 0);       \
  } while (0)

  GSTAGE(0, 0);
  GSTAGE(1, 32);
  const int nIt = K >> 5;
  int bi = 0, b2 = 2;  // it%3, (it+2)%3
  for (int it = 0; it < nIt; ++it) {
    if (it < nIt - 1) {
      asm volatile("s_waitcnt vmcnt(4)" ::: "memory");  // tile it's 4 done; it+1's fly
    } else {
      asm volatile("s_waitcnt vmcnt(0)" ::: "memory");
    }
    __builtin_amdgcn_s_barrier();  // prev reads done; tile it visible to all
    if (it + 2 < nIt) GSTAGE(b2, (it + 2) << 5);
    const bf16* As = (const bf16*)(smem + bi * 16384);
    const bf16* Bs = (const bf16*)(smem + bi * 16384 + 8192);
    bf16x8 af[4], bfv[4];
#pragma unroll
    for (int i = 0; i < 4; ++i) {
      af[i] = *(const bf16x8*)(As + (wr * 64 + i * 16 + l15) * 32 + lhi * 8);
      bfv[i] = *(const bf16x8*)(Bs + (wc * 64 + i * 16 + l15) * 32 + lhi * 8);
    }
    __builtin_amdgcn_s_setprio(1);
#pragma unroll
    for (int i = 0; i < 4; ++i)
#pragma unroll
      for (int j = 0; j < 4; ++j) acc[i][j] = mfma16(af[i], bfv[j], acc[i][j]);
    __builtin_amdgcn_s_setprio(0);
    bi = (bi == 2) ? 0 : bi + 1;
    b2 = (b2 == 2) ? 0 : b2 + 1;
  }
#undef GSTAGE

  if constexpr (BF16OUT) {
    __syncthreads();  // all waves done with last tile's LDS before overlay
    bf16* Cs = (bf16*)smem;  // [128][128] overlays buffers 0-1
#pragma unroll
    for (int i = 0; i < 4; ++i)
#pragma unroll
      for (int j = 0; j < 4; ++j) {
        int row = wr * 64 + i * 16 + lhi * 4;
        int col = wc * 64 + j * 16 + l15;
#pragma unroll
        for (int r = 0; r < 4; ++r) Cs[(row + r) * 128 + col] = tobf(acc[i][j][r]);
      }
    __syncthreads();
    bf16* C = (bf16*)Cout;
#pragma unroll
    for (int inst = 0; inst < 8; ++inst) {
      int flat = inst * 4096 + tid * 16;  // bytes over 32KB
      int row = flat >> 8, colb = flat & 255;
      *(u32x4*)((char*)C + ((size_t)(m0 + row) * Nn + n0) * 2 + colb) =
          *(const u32x4*)(smem + flat);
    }
  } else {
    float* C = (float*)Cout;
    float bj[4];
#pragma unroll
    for (int j = 0; j < 4; ++j) bj[j] = bias[n0 + wc * 64 + j * 16 + l15];
#pragma unroll
    for (int i = 0; i < 4; ++i)
#pragma unroll
      for (int j = 0; j < 4; ++j) {
        int row = m0 + wr * 64 + i * 16 + lhi * 4;
        int col = n0 + wc * 64 + j * 16 + l15;
#pragma unroll
        for (int r = 0; r < 4; ++r) C[(size_t)(row + r) * Nn + col] = acc[i][j][r] + bj[j];
      }
  }
}

// ---------------- RoPE + head reshape for Q,K ----------------
__global__ void k_rope(const bf16* __restrict__ Cq, const float* __restrict__ cs,
                       bf16* __restrict__ Qr, bf16* __restrict__ Kr) {
  int idx = blockIdx.x * 256 + threadIdx.x;  // 2^21
  int i = idx & 31;
  int h = (idx >> 5) & 15;
  int n = (idx >> 9) & 2047;
  int b = idx >> 20;
  const u32* src = (const u32*)(Cq + ((size_t)(b * SEQ + n)) * QKV3);
  float c = cs[((n << 5) + i) * 2], s = cs[((n << 5) + i) * 2 + 1];
  u32 qp = src[h * 32 + i];
  u32 kp = src[512 + h * 32 + i];
  u32 t;
  float q0, q1, kk0, kk1;
  t = qp << 16; __builtin_memcpy(&q0, &t, 4);
  t = qp & 0xffff0000u; __builtin_memcpy(&q1, &t, 4);
  t = kp << 16; __builtin_memcpy(&kk0, &t, 4);
  t = kp & 0xffff0000u; __builtin_memcpy(&kk1, &t, 4);
  bf16 qa = tobf(q0 * c - q1 * s), qb = tobf(q1 * c + q0 * s);
  bf16 ka = tobf(kk0 * c - kk1 * s), kb = tobf(kk1 * c + kk0 * s);
  unsigned short ua, ub;
  __builtin_memcpy(&ua, &qa, 2); __builtin_memcpy(&ub, &qb, 2);
  u32 qo = (u32)ua | ((u32)ub << 16);
  __builtin_memcpy(&ua, &ka, 2); __builtin_memcpy(&ub, &kb, 2);
  u32 ko = (u32)ua | ((u32)ub << 16);
  size_t o32 = ((size_t)(b * NH + h) * SEQ + n) * 32 + i;
  ((u32*)Qr)[o32] = qo;
  ((u32*)Kr)[o32] = ko;
}

// ---------------- V transpose: C_qkv v-part -> V^T [b][h][64][n] ----------------
__global__ void k_vtrans(const bf16* __restrict__ Cq, bf16* __restrict__ Vt) {
  __shared__ __attribute__((aligned(16))) bf16 t[64][72];
  int bid = blockIdx.x;  // b<<9 | h<<5 | nb
  int nb = bid & 31, h = (bid >> 5) & 15, b = bid >> 9;
  int n0 = nb << 6;
  int tid = threadIdx.x;
  int row = tid >> 2, c0 = (tid & 3) << 4;
  const bf16* s = Cq + ((size_t)(b * SEQ + n0 + row)) * QKV3 + 2048 + h * 64 + c0;
  bf16x8 a = *(const bf16x8*)s;
  bf16x8 bv = *(const bf16x8*)(s + 8);
#pragma unroll
  for (int e = 0; e < 8; ++e) { t[row][c0 + e] = a[e]; t[row][c0 + 8 + e] = bv[e]; }
  __syncthreads();
  bf16x8 o0, o1;
#pragma unroll
  for (int e = 0; e < 8; ++e) { o0[e] = t[c0 + e][row]; o1[e] = t[c0 + 8 + e][row]; }
  bf16* d = Vt + ((size_t)((b * NH + h) * 64 + row)) * SEQ + n0 + c0;
  *(bf16x8*)d = o0;
  *(bf16x8*)(d + 8) = o1;
}

// ---------------- Flash attention (split-K, 8 waves, counted-vmcnt pipeline) --
// Round-8 structure + T4: per pipe, K is 3-buffered and V 2-buffered. Issue
// order per iter is V(t+1) then K(t+2), so the queue at each iteration top is
// [K(t), V(t), K(t+1)] and vmcnt(2) completes exactly K(t)+V(t), leaving
// K(t+1) in flight ACROSS the barrier (no full drain until the tail).
__global__ __launch_bounds__(512, 4) void k_attn(const bf16* __restrict__ Qr,
                                                 const bf16* __restrict__ Kr,
                                                 const bf16* __restrict__ Vt,
                                                 bf16* __restrict__ AO) {
  // per pipe: K bufs 3x8KB at +0, V bufs 2x8KB at +24576 -> 40KB; 2 pipes = 80KB
  __shared__ __attribute__((aligned(16))) char lds[2][40960];
  // XCD swizzle: 512 blocks, 8 XCDs -> 64 consecutive works per XCD (4 heads)
  int wg = blockIdx.x;
  int work = (wg & 7) * 64 + (wg >> 3);
  int qc = work & 15, h = (work >> 4) & 15, b = work >> 8;
  int tid = threadIdx.x;
  int wv = tid >> 6, lane = tid & 63;
  int pipe = wv >> 2, wsub = wv & 3;
  int l31 = lane & 31, h5 = lane >> 5;
  int q0 = qc * 128 + wsub * 32;
  int kbase = pipe << 10;  // element offset of this pipe's k-half
  const bf16* Qb = Qr + ((size_t)(b * NH + h)) * SEQ * 64;
  const bf16* Kb = Kr + ((size_t)(b * NH + h)) * SEQ * 64;
  const bf16* Vb = Vt + ((size_t)(b * NH + h)) * 64 * SEQ;
  char* pb = lds[pipe];

  // staging addresses (2 K insts + 2 V insts per thread per tile; 256 thr/pipe)
  int ptid = tid & 255;
  int sf0 = ptid * 16, sf1 = 4096 + ptid * 16;  // flat byte offsets in 8KB region
  int sr0 = sf0 >> 7, sr1 = sf1 >> 7;
  int sc0 = (sf0 & 127) ^ ((sr0 & 7) << 4);
  int sc1 = (sf1 & 127) ^ ((sr1 & 7) << 4);
  size_t kgb0 = (size_t)sr0 * 64 + (sc0 >> 1), kgb1 = (size_t)sr1 * 64 + (sc1 >> 1);
  size_t vgb0 = (size_t)sr0 * SEQ + (sc0 >> 1), vgb1 = (size_t)sr1 * SEQ + (sc1 >> 1);

#define STAGE_K(bi_, kb_)                                                                     \
  do {                                                                                        \
    size_t ko_ = (size_t)(kbase + (kb_));                                                     \
    char* bb_ = pb + (bi_)*8192;                                                              \
    __builtin_amdgcn_global_load_lds(GPTR(Kb + ko_ * 64 + kgb0), SPTR(bb_ + sf0), 16, 0, 0);  \
    __builtin_amdgcn_global_load_lds(GPTR(Kb + ko_ * 64 + kgb1), SPTR(bb_ + sf1), 16, 0, 0);  \
  } while (0)
#define STAGE_V(bi_, kb_)                                                                     \
  do {                                                                                        \
    size_t ko_ = (size_t)(kbase + (kb_));                                                     \
    char* bb_ = pb + 24576 + (bi_)*8192;                                                      \
    __builtin_amdgcn_global_load_lds(GPTR(Vb + ko_ + vgb0), SPTR(bb_ + sf0), 16, 0, 0);       \
    __builtin_amdgcn_global_load_lds(GPTR(Vb + ko_ + vgb1), SPTR(bb_ + sf1), 16, 0, 0);       \
  } while (0)

  // Q B-frags: col=q=lane&31, k-dim d = s*16 + h5*8 + e
  bf16x8 qf[4];
#pragma unroll
  for (int s = 0; s < 4; ++s) qf[s] = *(const bf16x8*)(Qb + (q0 + l31) * 64 + s * 16 + h5 * 8);

  f32x16 acc0 = {}, acc1 = {};
  float ssum = 0.f;
  const float sc = 0.125f * 1.44269504f;  // 1/sqrt(64) * log2(e)
  const float FOFF = 8.0f;                // fixed log2-domain offset (scores bounded)
  const int sw = (l31 & 7) << 4;
  const int cbase = h5 * 16;

  // prologue in steady-state queue order: K(0), V(0), K(1)
  STAGE_K(0, 0);
  STAGE_V(0, 0);
  STAGE_K(1, 64);

  constexpr int NT = (SEQ / 2) / 64;  // 16 tiles per pipe
  int kc = 0, kc2 = 2;                // t%3, (t+2)%3
  for (int t = 0; t < NT; ++t) {
    if (t < NT - 1) {
      asm volatile("s_waitcnt vmcnt(2)" ::: "memory");  // K(t)+V(t) done; K(t+1) flies
    } else {
      asm volatile("s_waitcnt vmcnt(0)" ::: "memory");
    }
    __builtin_amdgcn_s_barrier();  // all waves' parts of tile t in LDS; t-1 reads done
    if (t + 1 < NT) STAGE_V((t + 1) & 1, (t + 1) * 64);
    if (t + 2 < NT) STAGE_K(kc2, (t + 2) * 64);
    char* cbK = pb + kc * 8192;
    char* cbV = pb + 24576 + (t & 1) * 8192;
    kc = (kc == 2) ? 0 : kc + 1;
    kc2 = (kc2 == 2) ? 0 : kc2 + 1;

    // ---- QK^T: S^T[k][q], two 32-k halves ----
    f32x16 st0 = {}, st1 = {};
    __builtin_amdgcn_s_setprio(1);
#pragma unroll
    for (int s = 0; s < 4; ++s) {
      bf16x8 kf0 = *(const bf16x8*)(cbK + l31 * 128 + ((s * 32 + cbase) ^ sw));
      bf16x8 kf1 = *(const bf16x8*)(cbK + 4096 + l31 * 128 + ((s * 32 + cbase) ^ sw));
      st0 = mfma32(kf0, qf[s], st0);
      st1 = mfma32(kf1, qf[s], st1);
    }
    __builtin_amdgcn_s_setprio(0);

    // ---- softmax numerator, fixed offset (lane owns q=l31) ----
    float p[32];
#pragma unroll
    for (int r = 0; r < 16; ++r) p[r] = __builtin_amdgcn_exp2f(fmaf(st0[r], sc, -FOFF));
#pragma unroll
    for (int r = 0; r < 16; ++r) p[16 + r] = __builtin_amdgcn_exp2f(fmaf(st1[r], sc, -FOFF));

    // ---- pack P to bf16 pairs: P32[i] = pack(p[2i], p[2i+1]) ----
    u32 P32[16];
#pragma unroll
    for (int i = 0; i < 16; ++i) {
      bf16 lo = tobf(p[2 * i]), hi = tobf(p[2 * i + 1]);
      unsigned short ul, uh;
      __builtin_memcpy(&ul, &lo, 2);
      __builtin_memcpy(&uh, &hi, 2);
      P32[i] = (u32)ul | ((u32)uh << 16);
    }
    // ssum from the bf16-ROUNDED values (normalization matches PV weights)
    float sm[16];
#pragma unroll
    for (int i = 0; i < 16; ++i) {
      u32 ulo = P32[i] << 16, uhi = P32[i] & 0xffff0000u;
      float flo, fhi;
      __builtin_memcpy(&flo, &ulo, 4);
      __builtin_memcpy(&fhi, &uhi, 4);
      sm[i] = flo + fhi;
    }
#pragma unroll
    for (int off = 8; off > 0; off >>= 1)
#pragma unroll
      for (int r = 0; r < off; ++r) sm[r] += sm[r + off];
    ssum += sm[0];

    // half-exchange: send what partner needs (8 shfls)
    const int evens[8] = {0, 1, 4, 5, 8, 9, 12, 13};
    const int odds[8] = {2, 3, 6, 7, 10, 11, 14, 15};
    u32 recv[8];
#pragma unroll
    for (int j = 0; j < 8; ++j) {
      u32 sv = h5 ? P32[evens[j]] : P32[odds[j]];
      recv[j] = (u32)__shfl_xor((int)sv, 32, 64);
    }

    // ---- PV: O^T[d][q] += V^T-frag x P^T-frag ----
    __builtin_amdgcn_s_setprio(1);
#pragma unroll
    for (int s2 = 0; s2 < 4; ++s2) {
      int x0 = ((s2 >> 1) << 3) + ((s2 & 1) << 2);  // 0,4,8,12
      u32 w0 = h5 ? recv[2 * s2] : P32[x0];
      u32 w1 = h5 ? recv[2 * s2 + 1] : P32[x0 + 1];
      u32 w2 = h5 ? P32[x0 + 2] : recv[2 * s2];
      u32 w3 = h5 ? P32[x0 + 3] : recv[2 * s2 + 1];
      u32x4 wv4 = {w0, w1, w2, w3};
      bf16x8 pfr = __builtin_bit_cast(bf16x8, wv4);
      bf16x8 vf0 = *(const bf16x8*)(cbV + l31 * 128 + ((s2 * 32 + cbase) ^ sw));
      bf16x8 vf1 = *(const bf16x8*)(cbV + 4096 + l31 * 128 + ((s2 * 32 + cbase) ^ sw));
      acc0 = mfma32(vf0, pfr, acc0);
      acc1 = mfma32(vf1, pfr, acc1);
    }
    __builtin_amdgcn_s_setprio(0);
  }

  // ---- split-K merge: pipe1 -> LDS -> pipe0 adds; then normalize+store ----
  __syncthreads();  // all staging reads done; LDS reusable
  float* cacc = (float*)&lds[0][0];                  // [4][64][36] padded
  float* csum = (float*)(&lds[0][0] + 36864);        // [4][64]
  int slot = (wsub * 64 + lane) * 36;
  if (pipe == 1) {
#pragma unroll
    for (int r = 0; r < 16; r += 4) {
      *(f32x4*)(cacc + slot + r) = f32x4{acc0[r], acc0[r + 1], acc0[r + 2], acc0[r + 3]};
      *(f32x4*)(cacc + slot + 16 + r) = f32x4{acc1[r], acc1[r + 1], acc1[r + 2], acc1[r + 3]};
    }
    csum[wsub * 64 + lane] = ssum;
  }
  __syncthreads();
  if (pipe == 0) {
#pragma unroll
    for (int r = 0; r < 16; r += 4) {
      f32x4 v0 = *(const f32x4*)(cacc + slot + r);
      f32x4 v1 = *(const f32x4*)(cacc + slot + 16 + r);
#pragma unroll
      for (int j = 0; j < 4; ++j) { acc0[r + j] += v0[j]; acc1[r + j] += v1[j]; }
    }
    ssum += csum[wsub * 64 + lane];
    ssum += __shfl_xor(ssum, 32, 64);
    float inv = 1.0f / ssum;
    size_t tok = (size_t)(b * SEQ + q0 + l31);
#pragma unroll
    for (int a = 0; a < 4; ++a) {
      bf16x4 ov0, ov1;
#pragma unroll
      for (int j = 0; j < 4; ++j) {
        ov0[j] = tobf(acc0[4 * a + j] * inv);
        ov1[j] = tobf(acc1[4 * a + j] * inv);
      }
      *(bf16x4*)(AO + tok * (NH * HD) + h * 64 + 8 * a + 4 * h5) = ov0;
      *(bf16x4*)(AO + tok * (NH * HD) + h * 64 + 32 + 8 * a + 4 * h5) = ov1;
    }
  }
#undef STAGE_K
#undef STAGE_V
}

// ---------------- launcher ----------------

extern "C" void kernel_launch(void* const* d_in, const int* in_sizes, int n_in,
                              void* d_out, int out_size, void* d_ws, size_t ws_size,
                              hipStream_t stream) {
  const float* hs = (const float*)d_in[0];
  const float* wqkv = (const float*)d_in[1];
  const float* wout = (const float*)d_in[2];
  const float* bout = (const float*)d_in[3];
  char* ws = (char*)d_ws;
  bf16* Xb = (bf16*)(ws + OXB);
  bf16* Wqkt = (bf16*)(ws + OWQ);
  bf16* Woutt = (bf16*)(ws + OWO);
  float* cs = (float*)(ws + OCS);
  bf16* Cqkv = (bf16*)(ws + OCQ);
  bf16* Qr = (bf16*)(ws + OQR);
  bf16* Kr = (bf16*)(ws + OKR);
  bf16* Vt = (bf16*)(ws + OVT);
  bf16* AO = (bf16*)(ws + OAO);

  k_costab<<<256, 256, 0, stream>>>(cs);
  k_cvt<<<(MTOK * DMODEL / 4 + 255) / 256, 256, 0, stream>>>(hs, Xb, MTOK * DMODEL / 4);
  k_trans<<<dim3(QKV3 / 32, DMODEL / 32), 256, 0, stream>>>(wqkv, Wqkt, DMODEL, QKV3);
  k_trans<<<dim3(DMODEL / 32, DMODEL / 32), 256, 0, stream>>>(wout, Woutt, DMODEL, DMODEL);
  k_gemm<1><<<(MTOK / 128) * (QKV3 / 128), 256, 0, stream>>>(Xb, Wqkt, Cqkv, nullptr, MTOK, QKV3, DMODEL);
  k_rope<<<(BATCH * SEQ * NH * 32) / 256, 256, 0, stream>>>(Cqkv, cs, Qr, Kr);
  k_vtrans<<<BATCH * NH * (SEQ / 64), 256, 0, stream>>>(Cqkv, Vt);
  k_attn<<<BATCH * NH * (SEQ / 128), 512, 0, stream>>>(Qr, Kr, Vt, AO);
  k_gemm<0><<<(MTOK / 128) * (DMODEL / 128), 256, 0, stream>>>(AO, Woutt, d_out, bout, MTOK, DMODEL, DMODEL);
}

// Round 11
// 151.800 us; speedup vs baseline: 1.4408x; 1.0406x over previous
//
#include <hip/hip_runtime.h>
#include <hip/hip_bf16.h>

typedef __bf16 bf16;
typedef unsigned int u32;
typedef __attribute__((ext_vector_type(4))) float f32x4;
typedef __attribute__((ext_vector_type(16))) float f32x16;
typedef __attribute__((ext_vector_type(8))) bf16 bf16x8;
typedef __attribute__((ext_vector_type(4))) bf16 bf16x4;
typedef __attribute__((ext_vector_type(4))) u32 u32x4;

#define GPTR(p) ((const __attribute__((address_space(1))) u32*)(p))
#define SPTR(p) ((__attribute__((address_space(3))) u32*)(p))

// Problem constants
constexpr int BATCH = 2, SEQ = 2048, DMODEL = 1024, NH = 16, HD = 64, QKV3 = 3072;
constexpr int MTOK = BATCH * SEQ;  // 4096 tokens

// Workspace layout (bytes)
constexpr size_t OXB = 0;                                       // X bf16 [4096][1024]
constexpr size_t OWQ = OXB + (size_t)MTOK * DMODEL * 2;         // Wqkv^T bf16 [3072][1024]
constexpr size_t OWO = OWQ + (size_t)QKV3 * DMODEL * 2;         // Wout^T bf16 [1024][1024]
constexpr size_t OCS = OWO + (size_t)DMODEL * DMODEL * 2;       // cos/sin f32 [2048][32][2]
constexpr size_t OCQ = OCS + (size_t)SEQ * 32 * 8;              // (unused now)
constexpr size_t OQR = OCQ + (size_t)MTOK * QKV3 * 2;           // Q roped [b][h][n][64]
constexpr size_t OKR = OQR + (size_t)BATCH * NH * SEQ * HD * 2; // K roped
constexpr size_t OVT = OKR + (size_t)BATCH * NH * SEQ * HD * 2; // V^T [b][h][64][n]
constexpr size_t OAO = OXB;                                     // attn out (aliases Xb, dead by then)

static __device__ __forceinline__ bf16 tobf(float x) { return (bf16)x; }
static __device__ __forceinline__ float tof(bf16 x) { return (float)x; }

static __device__ __forceinline__ f32x4 mfma16(bf16x8 a, bf16x8 b, f32x4 c) {
  return __builtin_amdgcn_mfma_f32_16x16x32_bf16(a, b, c, 0, 0, 0);
}
static __device__ __forceinline__ f32x16 mfma32(bf16x8 a, bf16x8 b, f32x16 c) {
  return __builtin_amdgcn_mfma_f32_32x32x16_bf16(a, b, c, 0, 0, 0);
}

// ---------------- prep kernels ----------------

__global__ void k_costab(float* __restrict__ cs) {
  int idx = blockIdx.x * 256 + threadIdx.x;  // 65536 = 2048*32
  int n = idx >> 5, i = idx & 31;
  float freq = powf(10000.0f, -(float)(2 * i) / 64.0f);
  float ang = (float)n * freq;
  float s, c;
  sincosf(ang, &s, &c);
  cs[idx * 2] = c;
  cs[idx * 2 + 1] = s;
}

__global__ void k_cvt(const float* __restrict__ x, bf16* __restrict__ y, int n4) {
  int i = blockIdx.x * 256 + threadIdx.x;
  if (i >= n4) return;
  float4 v = ((const float4*)x)[i];
  bf16x4 o = {tobf(v.x), tobf(v.y), tobf(v.z), tobf(v.w)};
  ((bf16x4*)y)[i] = o;
}

// transpose-convert: in f32 [R][C] -> out bf16 [C][R]
__global__ void k_trans(const float* __restrict__ in, bf16* __restrict__ out, int R, int C) {
  __shared__ float tile[32][33];
  int k0 = blockIdx.y * 32, n0 = blockIdx.x * 32;
  int tx = threadIdx.x & 31, ty = threadIdx.x >> 5;  // ty 0..7
#pragma unroll
  for (int r = ty; r < 32; r += 8) tile[r][tx] = in[(size_t)(k0 + r) * C + n0 + tx];
  __syncthreads();
#pragma unroll
  for (int r = ty; r < 32; r += 8) out[(size_t)(n0 + r) * R + k0 + tx] = tobf(tile[tx][r]);
}

// ---------------- GEMM2: A bf16 [M][K] x Bt bf16 [N][K] -> C f32 + bias ------
// 128x128 tile, BK=32, 3-buffer LDS, counted vmcnt(4), XCD-swizzled grid.

__global__ __launch_bounds__(256) void k_gemm2(const bf16* __restrict__ A, const bf16* __restrict__ Bt,
                                               float* __restrict__ C, const float* __restrict__ bias,
                                               int M, int Nn, int K) {
  __shared__ __attribute__((aligned(16))) char smem[49152];  // 3 x (As 8KB | Bs 8KB)
  const int nTn = Nn >> 7;
  int nwg = gridDim.x;
  int bid = blockIdx.x;
  int wgs = (bid & 7) * (nwg >> 3) + (bid >> 3);  // bijective XCD swizzle (nwg%8==0)
  const int m0 = (wgs / nTn) << 7;
  const int n0 = (wgs % nTn) << 7;
  const int tid = threadIdx.x;
  const int lane = tid & 63, w = tid >> 6;
  const int wr = w >> 1, wc = w & 1;
  const int l15 = lane & 15, lhi = lane >> 4;
  f32x4 acc[4][4] = {};

  const int flat0 = w * 1024 + lane * 16;  // byte offset in 8KB half-tile
  const int flat1 = flat0 + 4096;
  const int row0 = flat0 >> 6, ke0 = (flat0 & 63) >> 1;
  const int row1 = flat1 >> 6, ke1 = (flat1 & 63) >> 1;

#define GSTAGE(bb_, k0_)                                                                       \
  do {                                                                                         \
    __builtin_amdgcn_global_load_lds(GPTR(A + (size_t)(m0 + row0) * K + (k0_) + ke0),          \
                                     SPTR(smem + (bb_)*16384 + flat0), 16, 0, 0);              \
    __builtin_amdgcn_global_load_lds(GPTR(A + (size_t)(m0 + row1) * K + (k0_) + ke1),          \
                                     SPTR(smem + (bb_)*16384 + flat1), 16, 0, 0);              \
    __builtin_amdgcn_global_load_lds(GPTR(Bt + (size_t)(n0 + row0) * K + (k0_) + ke0),         \
                                     SPTR(smem + (bb_)*16384 + 8192 + flat0), 16, 0, 0);       \
    __builtin_amdgcn_global_load_lds(GPTR(Bt + (size_t)(n0 + row1) * K + (k0_) + ke1),         \
                                     SPTR(smem + (bb_)*16384 + 8192 + flat1), 16, 0, 0);       \
  } while (0)

  GSTAGE(0, 0);
  GSTAGE(1, 32);
  const int nIt = K >> 5;
  int bi = 0, b2 = 2;
  for (int it = 0; it < nIt; ++it) {
    if (it < nIt - 1) {
      asm volatile("s_waitcnt vmcnt(4)" ::: "memory");
    } else {
      asm volatile("s_waitcnt vmcnt(0)" ::: "memory");
    }
    __builtin_amdgcn_s_barrier();
    if (it + 2 < nIt) GSTAGE(b2, (it + 2) << 5);
    const bf16* As = (const bf16*)(smem + bi * 16384);
    const bf16* Bs = (const bf16*)(smem + bi * 16384 + 8192);
    bf16x8 af[4], bfv[4];
#pragma unroll
    for (int i = 0; i < 4; ++i) {
      af[i] = *(const bf16x8*)(As + (wr * 64 + i * 16 + l15) * 32 + lhi * 8);
      bfv[i] = *(const bf16x8*)(Bs + (wc * 64 + i * 16 + l15) * 32 + lhi * 8);
    }
    __builtin_amdgcn_s_setprio(1);
#pragma unroll
    for (int i = 0; i < 4; ++i)
#pragma unroll
      for (int j = 0; j < 4; ++j) acc[i][j] = mfma16(af[i], bfv[j], acc[i][j]);
    __builtin_amdgcn_s_setprio(0);
    bi = (bi == 2) ? 0 : bi + 1;
    b2 = (b2 == 2) ? 0 : b2 + 1;
  }
#undef GSTAGE

  float bj[4];
#pragma unroll
  for (int j = 0; j < 4; ++j) bj[j] = bias[n0 + wc * 64 + j * 16 + l15];
#pragma unroll
  for (int i = 0; i < 4; ++i)
#pragma unroll
    for (int j = 0; j < 4; ++j) {
      int row = m0 + wr * 64 + i * 16 + lhi * 4;
      int col = n0 + wc * 64 + j * 16 + l15;
#pragma unroll
      for (int r = 0; r < 4; ++r) C[(size_t)(row + r) * Nn + col] = acc[i][j][r] + bj[j];
    }
}

// ---------------- GEMM1 fused: X x Wqkv^T -> RoPE(Q), RoPE(K), V^T ----------
// Same 3-buffer counted-vmcnt k-loop. Epilogue: each 128-col tile lies wholly
// in the q/k/v third. q/k: Cs round-trip + RoPE during coalesced write to
// Qr/Kr[b][h][n][64] (numerically identical to the old k_rope: same bf16
// inputs, fp32 rotation). v: acc written TRANSPOSED into LDS (chunk-XOR
// swizzle), then coalesced 16B rows out to Vt[b][h][64][n] (old k_vtrans).

__global__ __launch_bounds__(256) void k_gemm1f(const bf16* __restrict__ A, const bf16* __restrict__ Bt,
                                                const float* __restrict__ cs,
                                                bf16* __restrict__ Qr, bf16* __restrict__ Kr,
                                                bf16* __restrict__ Vt) {
  constexpr int K = DMODEL, Nn = QKV3;
  __shared__ __attribute__((aligned(16))) char smem[49152];
  const int nTn = Nn >> 7;  // 24
  int nwg = gridDim.x;
  int bid = blockIdx.x;
  int wgs = (bid & 7) * (nwg >> 3) + (bid >> 3);
  const int m0 = (wgs / nTn) << 7;
  const int n0 = (wgs % nTn) << 7;
  const int tid = threadIdx.x;
  const int lane = tid & 63, w = tid >> 6;
  const int wr = w >> 1, wc = w & 1;
  const int l15 = lane & 15, lhi = lane >> 4;
  f32x4 acc[4][4] = {};

  const int flat0 = w * 1024 + lane * 16;
  const int flat1 = flat0 + 4096;
  const int row0 = flat0 >> 6, ke0 = (flat0 & 63) >> 1;
  const int row1 = flat1 >> 6, ke1 = (flat1 & 63) >> 1;

#define GSTAGE(bb_, k0_)                                                                       \
  do {                                                                                         \
    __builtin_amdgcn_global_load_lds(GPTR(A + (size_t)(m0 + row0) * K + (k0_) + ke0),          \
                                     SPTR(smem + (bb_)*16384 + flat0), 16, 0, 0);              \
    __builtin_amdgcn_global_load_lds(GPTR(A + (size_t)(m0 + row1) * K + (k0_) + ke1),          \
                                     SPTR(smem + (bb_)*16384 + flat1), 16, 0, 0);              \
    __builtin_amdgcn_global_load_lds(GPTR(Bt + (size_t)(n0 + row0) * K + (k0_) + ke0),         \
                                     SPTR(smem + (bb_)*16384 + 8192 + flat0), 16, 0, 0);       \
    __builtin_amdgcn_global_load_lds(GPTR(Bt + (size_t)(n0 + row1) * K + (k0_) + ke1),         \
                                     SPTR(smem + (bb_)*16384 + 8192 + flat1), 16, 0, 0);       \
  } while (0)

  GSTAGE(0, 0);
  GSTAGE(1, 32);
  const int nIt = K >> 5;  // 32
  int bi = 0, b2 = 2;
  for (int it = 0; it < nIt; ++it) {
    if (it < nIt - 1) {
      asm volatile("s_waitcnt vmcnt(4)" ::: "memory");
    } else {
      asm volatile("s_waitcnt vmcnt(0)" ::: "memory");
    }
    __builtin_amdgcn_s_barrier();
    if (it + 2 < nIt) GSTAGE(b2, (it + 2) << 5);
    const bf16* As = (const bf16*)(smem + bi * 16384);
    const bf16* Bs = (const bf16*)(smem + bi * 16384 + 8192);
    bf16x8 af[4], bfv[4];
#pragma unroll
    for (int i = 0; i < 4; ++i) {
      af[i] = *(const bf16x8*)(As + (wr * 64 + i * 16 + l15) * 32 + lhi * 8);
      bfv[i] = *(const bf16x8*)(Bs + (wc * 64 + i * 16 + l15) * 32 + lhi * 8);
    }
    __builtin_amdgcn_s_setprio(1);
#pragma unroll
    for (int i = 0; i < 4; ++i)
#pragma unroll
      for (int j = 0; j < 4; ++j) acc[i][j] = mfma16(af[i], bfv[j], acc[i][j]);
    __builtin_amdgcn_s_setprio(0);
    bi = (bi == 2) ? 0 : bi + 1;
    b2 = (b2 == 2) ? 0 : b2 + 1;
  }
#undef GSTAGE

  __syncthreads();  // k-loop LDS reads done before overlay
  const int part = n0 >> 10;  // 0=q, 1=k, 2=v
  const int b = m0 >> 11;     // tiles never straddle the batch boundary

  if (part < 2) {
    bf16* Cs = (bf16*)smem;  // [128][128]
#pragma unroll
    for (int i = 0; i < 4; ++i)
#pragma unroll
      for (int j = 0; j < 4; ++j) {
        int row = wr * 64 + i * 16 + lhi * 4;
        int col = wc * 64 + j * 16 + l15;
#pragma unroll
        for (int r = 0; r < 4; ++r) Cs[(row + r) * 128 + col] = tobf(acc[i][j][r]);
      }
    __syncthreads();
    bf16* dst = part == 0 ? Qr : Kr;
#pragma unroll
    for (int inst = 0; inst < 8; ++inst) {
      int flat = inst * 4096 + tid * 16;
      int row = flat >> 8, c0 = (flat & 255) >> 1;  // c0: multiple of 8
      int n = (m0 + row) & 2047;
      int gc = (n0 & 1023) + c0;
      int h = gc >> 6, d0 = gc & 63;
      u32x4 v = *(const u32x4*)(smem + flat);
      const float* cp = cs + (((n << 5) + (d0 >> 1)) << 1);
      f32x4 csA = *(const f32x4*)cp;        // c0,s0,c1,s1
      f32x4 csB = *(const f32x4*)(cp + 4);  // c2,s2,c3,s3
      u32x4 ow;
#pragma unroll
      for (int j = 0; j < 4; ++j) {
        float cc = (j == 0) ? csA[0] : (j == 1) ? csA[2] : (j == 2) ? csB[0] : csB[2];
        float sn = (j == 0) ? csA[1] : (j == 1) ? csA[3] : (j == 2) ? csB[1] : csB[3];
        u32 pw = v[j];
        u32 tl = pw << 16, th = pw & 0xffff0000u;
        float a0, a1;
        __builtin_memcpy(&a0, &tl, 4);
        __builtin_memcpy(&a1, &th, 4);
        bf16 o0 = tobf(a0 * cc - a1 * sn);
        bf16 o1 = tobf(a1 * cc + a0 * sn);
        unsigned short u0, u1;
        __builtin_memcpy(&u0, &o0, 2);
        __builtin_memcpy(&u1, &o1, 2);
        ow[j] = (u32)u0 | ((u32)u1 << 16);
      }
      *(u32x4*)(dst + (((size_t)(b * 16 + h) * 2048 + n) << 6) + d0) = ow;
    }
  } else {
    // v: transposed + chunk-XOR-swizzled staging, then coalesced rows out
#pragma unroll
    for (int i = 0; i < 4; ++i)
#pragma unroll
      for (int j = 0; j < 4; ++j) {
        int col = wc * 64 + j * 16 + l15;  // head-dim (tile-local row of Vt)
#pragma unroll
        for (int r = 0; r < 4; ++r) {
          int row = wr * 64 + i * 16 + lhi * 4 + r;  // token
          int byte = (col << 8) + ((((row >> 3) ^ (col & 7)) << 4) | ((row & 7) << 1));
          *(bf16*)(smem + byte) = tobf(acc[i][j][r]);
        }
      }
    __syncthreads();
#pragma unroll
    for (int inst = 0; inst < 8; ++inst) {
      int flat = inst * 4096 + tid * 16;
      int c = flat >> 8;               // head-dim row
      int rr0 = (flat & 255) >> 1;     // token start, multiple of 8
      u32x4 vv = *(const u32x4*)(smem + (c << 8) + ((((rr0 >> 3) ^ (c & 7)) << 4)));
      int gc = (n0 & 1023) + c;
      int h = gc >> 6, dd = gc & 63;
      *(u32x4*)(Vt + (((size_t)(b * 16 + h) * 64 + dd) << 11) + (m0 & 2047) + rr0) = vv;
    }
  }
}

// ---------------- Flash attention (split-K, 8 waves, counted-vmcnt pipeline) --
// (unchanged from round 9)
__global__ __launch_bounds__(512, 4) void k_attn(const bf16* __restrict__ Qr,
                                                 const bf16* __restrict__ Kr,
                                                 const bf16* __restrict__ Vt,
                                                 bf16* __restrict__ AO) {
  __shared__ __attribute__((aligned(16))) char lds[2][40960];
  int wg = blockIdx.x;
  int work = (wg & 7) * 64 + (wg >> 3);
  int qc = work & 15, h = (work >> 4) & 15, b = work >> 8;
  int tid = threadIdx.x;
  int wv = tid >> 6, lane = tid & 63;
  int pipe = wv >> 2, wsub = wv & 3;
  int l31 = lane & 31, h5 = lane >> 5;
  int q0 = qc * 128 + wsub * 32;
  int kbase = pipe << 10;
  const bf16* Qb = Qr + ((size_t)(b * NH + h)) * SEQ * 64;
  const bf16* Kb = Kr + ((size_t)(b * NH + h)) * SEQ * 64;
  const bf16* Vb = Vt + ((size_t)(b * NH + h)) * 64 * SEQ;
  char* pb = lds[pipe];

  int ptid = tid & 255;
  int sf0 = ptid * 16, sf1 = 4096 + ptid * 16;
  int sr0 = sf0 >> 7, sr1 = sf1 >> 7;
  int sc0 = (sf0 & 127) ^ ((sr0 & 7) << 4);
  int sc1 = (sf1 & 127) ^ ((sr1 & 7) << 4);
  size_t kgb0 = (size_t)sr0 * 64 + (sc0 >> 1), kgb1 = (size_t)sr1 * 64 + (sc1 >> 1);
  size_t vgb0 = (size_t)sr0 * SEQ + (sc0 >> 1), vgb1 = (size_t)sr1 * SEQ + (sc1 >> 1);

#define STAGE_K(bi_, kb_)                                                                     \
  do {                                                                                        \
    size_t ko_ = (size_t)(kbase + (kb_));                                                     \
    char* bb_ = pb + (bi_)*8192;                                                              \
    __builtin_amdgcn_global_load_lds(GPTR(Kb + ko_ * 64 + kgb0), SPTR(bb_ + sf0), 16, 0, 0);  \
    __builtin_amdgcn_global_load_lds(GPTR(Kb + ko_ * 64 + kgb1), SPTR(bb_ + sf1), 16, 0, 0);  \
  } while (0)
#define STAGE_V(bi_, kb_)                                                                     \
  do {                                                                                        \
    size_t ko_ = (size_t)(kbase + (kb_));                                                     \
    char* bb_ = pb + 24576 + (bi_)*8192;                                                      \
    __builtin_amdgcn_global_load_lds(GPTR(Vb + ko_ + vgb0), SPTR(bb_ + sf0), 16, 0, 0);       \
    __builtin_amdgcn_global_load_lds(GPTR(Vb + ko_ + vgb1), SPTR(bb_ + sf1), 16, 0, 0);       \
  } while (0)

  bf16x8 qf[4];
#pragma unroll
  for (int s = 0; s < 4; ++s) qf[s] = *(const bf16x8*)(Qb + (q0 + l31) * 64 + s * 16 + h5 * 8);

  f32x16 acc0 = {}, acc1 = {};
  float ssum = 0.f;
  const float sc = 0.125f * 1.44269504f;
  const float FOFF = 8.0f;
  const int sw = (l31 & 7) << 4;
  const int cbase = h5 * 16;

  STAGE_K(0, 0);
  STAGE_V(0, 0);
  STAGE_K(1, 64);

  constexpr int NT = (SEQ / 2) / 64;
  int kc = 0, kc2 = 2;
  for (int t = 0; t < NT; ++t) {
    if (t < NT - 1) {
      asm volatile("s_waitcnt vmcnt(2)" ::: "memory");
    } else {
      asm volatile("s_waitcnt vmcnt(0)" ::: "memory");
    }
    __builtin_amdgcn_s_barrier();
    if (t + 1 < NT) STAGE_V((t + 1) & 1, (t + 1) * 64);
    if (t + 2 < NT) STAGE_K(kc2, (t + 2) * 64);
    char* cbK = pb + kc * 8192;
    char* cbV = pb + 24576 + (t & 1) * 8192;
    kc = (kc == 2) ? 0 : kc + 1;
    kc2 = (kc2 == 2) ? 0 : kc2 + 1;

    f32x16 st0 = {}, st1 = {};
    __builtin_amdgcn_s_setprio(1);
#pragma unroll
    for (int s = 0; s < 4; ++s) {
      bf16x8 kf0 = *(const bf16x8*)(cbK + l31 * 128 + ((s * 32 + cbase) ^ sw));
      bf16x8 kf1 = *(const bf16x8*)(cbK + 4096 + l31 * 128 + ((s * 32 + cbase) ^ sw));
      st0 = mfma32(kf0, qf[s], st0);
      st1 = mfma32(kf1, qf[s], st1);
    }
    __builtin_amdgcn_s_setprio(0);

    float p[32];
#pragma unroll
    for (int r = 0; r < 16; ++r) p[r] = __builtin_amdgcn_exp2f(fmaf(st0[r], sc, -FOFF));
#pragma unroll
    for (int r = 0; r < 16; ++r) p[16 + r] = __builtin_amdgcn_exp2f(fmaf(st1[r], sc, -FOFF));

    u32 P32[16];
#pragma unroll
    for (int i = 0; i < 16; ++i) {
      bf16 lo = tobf(p[2 * i]), hi = tobf(p[2 * i + 1]);
      unsigned short ul, uh;
      __builtin_memcpy(&ul, &lo, 2);
      __builtin_memcpy(&uh, &hi, 2);
      P32[i] = (u32)ul | ((u32)uh << 16);
    }
    float sm[16];
#pragma unroll
    for (int i = 0; i < 16; ++i) {
      u32 ulo = P32[i] << 16, uhi = P32[i] & 0xffff0000u;
      float flo, fhi;
      __builtin_memcpy(&flo, &ulo, 4);
      __builtin_memcpy(&fhi, &uhi, 4);
      sm[i] = flo + fhi;
    }
#pragma unroll
    for (int off = 8; off > 0; off >>= 1)
#pragma unroll
      for (int r = 0; r < off; ++r) sm[r] += sm[r + off];
    ssum += sm[0];

    const int evens[8] = {0, 1, 4, 5, 8, 9, 12, 13};
    const int odds[8] = {2, 3, 6, 7, 10, 11, 14, 15};
    u32 recv[8];
#pragma unroll
    for (int j = 0; j < 8; ++j) {
      u32 sv = h5 ? P32[evens[j]] : P32[odds[j]];
      recv[j] = (u32)__shfl_xor((int)sv, 32, 64);
    }

    __builtin_amdgcn_s_setprio(1);
#pragma unroll
    for (int s2 = 0; s2 < 4; ++s2) {
      int x0 = ((s2 >> 1) << 3) + ((s2 & 1) << 2);
      u32 w0 = h5 ? recv[2 * s2] : P32[x0];
      u32 w1 = h5 ? recv[2 * s2 + 1] : P32[x0 + 1];
      u32 w2 = h5 ? P32[x0 + 2] : recv[2 * s2];
      u32 w3 = h5 ? P32[x0 + 3] : recv[2 * s2 + 1];
      u32x4 wv4 = {w0, w1, w2, w3};
      bf16x8 pfr = __builtin_bit_cast(bf16x8, wv4);
      bf16x8 vf0 = *(const bf16x8*)(cbV + l31 * 128 + ((s2 * 32 + cbase) ^ sw));
      bf16x8 vf1 = *(const bf16x8*)(cbV + 4096 + l31 * 128 + ((s2 * 32 + cbase) ^ sw));
      acc0 = mfma32(vf0, pfr, acc0);
      acc1 = mfma32(vf1, pfr, acc1);
    }
    __builtin_amdgcn_s_setprio(0);
  }

  __syncthreads();
  float* cacc = (float*)&lds[0][0];
  float* csum = (float*)(&lds[0][0] + 36864);
  int slot = (wsub * 64 + lane) * 36;
  if (pipe == 1) {
#pragma unroll
    for (int r = 0; r < 16; r += 4) {
      *(f32x4*)(cacc + slot + r) = f32x4{acc0[r], acc0[r + 1], acc0[r + 2], acc0[r + 3]};
      *(f32x4*)(cacc + slot + 16 + r) = f32x4{acc1[r], acc1[r + 1], acc1[r + 2], acc1[r + 3]};
    }
    csum[wsub * 64 + lane] = ssum;
  }
  __syncthreads();
  if (pipe == 0) {
#pragma unroll
    for (int r = 0; r < 16; r += 4) {
      f32x4 v0 = *(const f32x4*)(cacc + slot + r);
      f32x4 v1 = *(const f32x4*)(cacc + slot + 16 + r);
#pragma unroll
      for (int j = 0; j < 4; ++j) { acc0[r + j] += v0[j]; acc1[r + j] += v1[j]; }
    }
    ssum += csum[wsub * 64 + lane];
    ssum += __shfl_xor(ssum, 32, 64);
    float inv = 1.0f / ssum;
    size_t tok = (size_t)(b * SEQ + q0 + l31);
#pragma unroll
    for (int a = 0; a < 4; ++a) {
      bf16x4 ov0, ov1;
#pragma unroll
      for (int j = 0; j < 4; ++j) {
        ov0[j] = tobf(acc0[4 * a + j] * inv);
        ov1[j] = tobf(acc1[4 * a + j] * inv);
      }
      *(bf16x4*)(AO + tok * (NH * HD) + h * 64 + 8 * a + 4 * h5) = ov0;
      *(bf16x4*)(AO + tok * (NH * HD) + h * 64 + 32 + 8 * a + 4 * h5) = ov1;
    }
  }
#undef STAGE_K
#undef STAGE_V
}

// ---------------- launcher ----------------

extern "C" void kernel_launch(void* const* d_in, const int* in_sizes, int n_in,
                              void* d_out, int out_size, void* d_ws, size_t ws_size,
                              hipStream_t stream) {
  const float* hs = (const float*)d_in[0];
  const float* wqkv = (const float*)d_in[1];
  const float* wout = (const float*)d_in[2];
  const float* bout = (const float*)d_in[3];
  char* ws = (char*)d_ws;
  bf16* Xb = (bf16*)(ws + OXB);
  bf16* Wqkt = (bf16*)(ws + OWQ);
  bf16* Woutt = (bf16*)(ws + OWO);
  float* cs = (float*)(ws + OCS);
  bf16* Qr = (bf16*)(ws + OQR);
  bf16* Kr = (bf16*)(ws + OKR);
  bf16* Vt = (bf16*)(ws + OVT);
  bf16* AO = (bf16*)(ws + OAO);

  k_costab<<<256, 256, 0, stream>>>(cs);
  k_cvt<<<(MTOK * DMODEL / 4 + 255) / 256, 256, 0, stream>>>(hs, Xb, MTOK * DMODEL / 4);
  k_trans<<<dim3(QKV3 / 32, DMODEL / 32), 256, 0, stream>>>(wqkv, Wqkt, DMODEL, QKV3);
  k_trans<<<dim3(DMODEL / 32, DMODEL / 32), 256, 0, stream>>>(wout, Woutt, DMODEL, DMODEL);
  k_gemm1f<<<(MTOK / 128) * (QKV3 / 128), 256, 0, stream>>>(Xb, Wqkt, cs, Qr, Kr, Vt);
  k_attn<<<BATCH * NH * (SEQ / 128), 512, 0, stream>>>(Qr, Kr, Vt, AO);
  k_gemm2<<<(MTOK / 128) * (DMODEL / 128), 256, 0, stream>>>(AO, Woutt, (float*)d_out, bout, MTOK, DMODEL, DMODEL);
}

// Round 12
// 117.642 us; speedup vs baseline: 1.8592x; 1.2904x over previous
//
#include <hip/hip_runtime.h>
#include <hip/hip_bf16.h>

typedef __bf16 bf16;
typedef unsigned int u32;
typedef __attribute__((ext_vector_type(4))) float f32x4;
typedef __attribute__((ext_vector_type(16))) float f32x16;
typedef __attribute__((ext_vector_type(8))) bf16 bf16x8;
typedef __attribute__((ext_vector_type(4))) bf16 bf16x4;
typedef __attribute__((ext_vector_type(2))) bf16 bf16x2;
typedef __attribute__((ext_vector_type(4))) u32 u32x4;
typedef __attribute__((ext_vector_type(2))) u32 u32x2;

#define GPTR(p) ((const __attribute__((address_space(1))) u32*)(p))
#define SPTR(p) ((__attribute__((address_space(3))) u32*)(p))

#if __has_builtin(__builtin_amdgcn_permlane32_swap)
#define HAVE_PLSWAP 1
#else
#define HAVE_PLSWAP 0
#endif
#if __has_builtin(__builtin_amdgcn_fdot2_f32_bf16)
#define HAVE_DOT2 1
#else
#define HAVE_DOT2 0
#endif

// Problem constants
constexpr int BATCH = 2, SEQ = 2048, DMODEL = 1024, NH = 16, HD = 64, QKV3 = 3072;
constexpr int MTOK = BATCH * SEQ;  // 4096 tokens

// Workspace layout (bytes)
constexpr size_t OXB = 0;                                       // X bf16 [4096][1024]
constexpr size_t OWQ = OXB + (size_t)MTOK * DMODEL * 2;         // Wqkv^T bf16 [3072][1024]
constexpr size_t OWO = OWQ + (size_t)QKV3 * DMODEL * 2;         // Wout^T bf16 [1024][1024]
constexpr size_t OCS = OWO + (size_t)DMODEL * DMODEL * 2;       // cos/sin f32 [2048][32][2]
constexpr size_t OCQ = OCS + (size_t)SEQ * 32 * 8;              // (hole)
constexpr size_t OQR = OCQ + (size_t)MTOK * QKV3 * 2;           // Q roped [b][h][n][64]
constexpr size_t OKR = OQR + (size_t)BATCH * NH * SEQ * HD * 2; // K roped
constexpr size_t OVT = OKR + (size_t)BATCH * NH * SEQ * HD * 2; // V^T [b][h][64][n]
constexpr size_t OAO = OXB;                                     // attn out (aliases Xb, dead by then)

static __device__ __forceinline__ bf16 tobf(float x) { return (bf16)x; }
static __device__ __forceinline__ float tof(bf16 x) { return (float)x; }

static __device__ __forceinline__ f32x4 mfma16(bf16x8 a, bf16x8 b, f32x4 c) {
  return __builtin_amdgcn_mfma_f32_16x16x32_bf16(a, b, c, 0, 0, 0);
}
static __device__ __forceinline__ f32x16 mfma32(bf16x8 a, bf16x8 b, f32x16 c) {
  return __builtin_amdgcn_mfma_f32_32x32x16_bf16(a, b, c, 0, 0, 0);
}

// ---------------- fused prep kernel (costab | cvt | transW_qkv | transW_out) --
// Sections by blockIdx range; each block stays wholly in one section.
__global__ void k_prep(const float* __restrict__ hs, const float* __restrict__ wqkv,
                       const float* __restrict__ wout, float* __restrict__ cs,
                       bf16* __restrict__ Xb, bf16* __restrict__ Wqkt,
                       bf16* __restrict__ Woutt) {
  __shared__ float tile[32][33];
  int blk = blockIdx.x, tid = threadIdx.x;
  if (blk < 256) {
    // cos/sin table: 2048 x 32 pairs
    int idx = blk * 256 + tid;
    int n = idx >> 5, i = idx & 31;
    float freq = powf(10000.0f, -(float)(2 * i) / 64.0f);
    float ang = (float)n * freq;
    float s, c;
    sincosf(ang, &s, &c);
    cs[idx * 2] = c;
    cs[idx * 2 + 1] = s;
  } else if (blk < 256 + 4096) {
    // X f32 -> bf16 (float4-wide, exactly 4096*256 items)
    int i = (blk - 256) * 256 + tid;
    float4 v = ((const float4*)hs)[i];
    bf16x4 o = {tobf(v.x), tobf(v.y), tobf(v.z), tobf(v.w)};
    ((bf16x4*)Xb)[i] = o;
  } else {
    const float* in;
    bf16* out;
    int R, C, n0, k0;
    if (blk < 256 + 4096 + 3072) {
      int t = blk - 4352;
      in = wqkv; out = Wqkt; R = DMODEL; C = QKV3;
      n0 = (t % 96) * 32; k0 = (t / 96) * 32;
    } else {
      int t = blk - 7424;
      in = wout; out = Woutt; R = DMODEL; C = DMODEL;
      n0 = (t & 31) * 32; k0 = (t >> 5) * 32;
    }
    int tx = tid & 31, ty = tid >> 5;  // ty 0..7
#pragma unroll
    for (int r = ty; r < 32; r += 8) tile[r][tx] = in[(size_t)(k0 + r) * C + n0 + tx];
    __syncthreads();
#pragma unroll
    for (int r = ty; r < 32; r += 8) out[(size_t)(n0 + r) * R + k0 + tx] = tobf(tile[tx][r]);
  }
}

// ---------------- GEMM2: A bf16 [M][K] x Bt bf16 [N][K] -> C f32 + bias ------
// 128x128 tile, BK=32, 3-buffer LDS, counted vmcnt(4), XCD-swizzled grid.

__global__ __launch_bounds__(256) void k_gemm2(const bf16* __restrict__ A, const bf16* __restrict__ Bt,
                                               float* __restrict__ C, const float* __restrict__ bias,
                                               int M, int Nn, int K) {
  __shared__ __attribute__((aligned(16))) char smem[49152];  // 3 x (As 8KB | Bs 8KB)
  const int nTn = Nn >> 7;
  int nwg = gridDim.x;
  int bid = blockIdx.x;
  int wgs = (bid & 7) * (nwg >> 3) + (bid >> 3);  // bijective XCD swizzle (nwg%8==0)
  const int m0 = (wgs / nTn) << 7;
  const int n0 = (wgs % nTn) << 7;
  const int tid = threadIdx.x;
  const int lane = tid & 63, w = tid >> 6;
  const int wr = w >> 1, wc = w & 1;
  const int l15 = lane & 15, lhi = lane >> 4;
  f32x4 acc[4][4] = {};

  const int flat0 = w * 1024 + lane * 16;  // byte offset in 8KB half-tile
  const int flat1 = flat0 + 4096;
  const int row0 = flat0 >> 6, ke0 = (flat0 & 63) >> 1;
  const int row1 = flat1 >> 6, ke1 = (flat1 & 63) >> 1;

#define GSTAGE(bb_, k0_)                                                                       \
  do {                                                                                         \
    __builtin_amdgcn_global_load_lds(GPTR(A + (size_t)(m0 + row0) * K + (k0_) + ke0),          \
                                     SPTR(smem + (bb_)*16384 + flat0), 16, 0, 0);              \
    __builtin_amdgcn_global_load_lds(GPTR(A + (size_t)(m0 + row1) * K + (k0_) + ke1),          \
                                     SPTR(smem + (bb_)*16384 + flat1), 16, 0, 0);              \
    __builtin_amdgcn_global_load_lds(GPTR(Bt + (size_t)(n0 + row0) * K + (k0_) + ke0),         \
                                     SPTR(smem + (bb_)*16384 + 8192 + flat0), 16, 0, 0);       \
    __builtin_amdgcn_global_load_lds(GPTR(Bt + (size_t)(n0 + row1) * K + (k0_) + ke1),         \
                                     SPTR(smem + (bb_)*16384 + 8192 + flat1), 16, 0, 0);       \
  } while (0)

  GSTAGE(0, 0);
  GSTAGE(1, 32);
  const int nIt = K >> 5;
  int bi = 0, b2 = 2;
  for (int it = 0; it < nIt; ++it) {
    if (it < nIt - 1) {
      asm volatile("s_waitcnt vmcnt(4)" ::: "memory");
    } else {
      asm volatile("s_waitcnt vmcnt(0)" ::: "memory");
    }
    __builtin_amdgcn_s_barrier();
    if (it + 2 < nIt) GSTAGE(b2, (it + 2) << 5);
    const bf16* As = (const bf16*)(smem + bi * 16384);
    const bf16* Bs = (const bf16*)(smem + bi * 16384 + 8192);
    bf16x8 af[4], bfv[4];
#pragma unroll
    for (int i = 0; i < 4; ++i) {
      af[i] = *(const bf16x8*)(As + (wr * 64 + i * 16 + l15) * 32 + lhi * 8);
      bfv[i] = *(const bf16x8*)(Bs + (wc * 64 + i * 16 + l15) * 32 + lhi * 8);
    }
    __builtin_amdgcn_s_setprio(1);
#pragma unroll
    for (int i = 0; i < 4; ++i)
#pragma unroll
      for (int j = 0; j < 4; ++j) acc[i][j] = mfma16(af[i], bfv[j], acc[i][j]);
    __builtin_amdgcn_s_setprio(0);
    bi = (bi == 2) ? 0 : bi + 1;
    b2 = (b2 == 2) ? 0 : b2 + 1;
  }
#undef GSTAGE

  float bj[4];
#pragma unroll
  for (int j = 0; j < 4; ++j) bj[j] = bias[n0 + wc * 64 + j * 16 + l15];
#pragma unroll
  for (int i = 0; i < 4; ++i)
#pragma unroll
    for (int j = 0; j < 4; ++j) {
      int row = m0 + wr * 64 + i * 16 + lhi * 4;
      int col = n0 + wc * 64 + j * 16 + l15;
#pragma unroll
      for (int r = 0; r < 4; ++r) C[(size_t)(row + r) * Nn + col] = acc[i][j][r] + bj[j];
    }
}

// ---------------- GEMM1 fused: X x Wqkv^T -> RoPE(Q), RoPE(K), V^T ----------
// (unchanged from round 11)

__global__ __launch_bounds__(256) void k_gemm1f(const bf16* __restrict__ A, const bf16* __restrict__ Bt,
                                                const float* __restrict__ cs,
                                                bf16* __restrict__ Qr, bf16* __restrict__ Kr,
                                                bf16* __restrict__ Vt) {
  constexpr int K = DMODEL, Nn = QKV3;
  __shared__ __attribute__((aligned(16))) char smem[49152];
  const int nTn = Nn >> 7;  // 24
  int nwg = gridDim.x;
  int bid = blockIdx.x;
  int wgs = (bid & 7) * (nwg >> 3) + (bid >> 3);
  const int m0 = (wgs / nTn) << 7;
  const int n0 = (wgs % nTn) << 7;
  const int tid = threadIdx.x;
  const int lane = tid & 63, w = tid >> 6;
  const int wr = w >> 1, wc = w & 1;
  const int l15 = lane & 15, lhi = lane >> 4;
  f32x4 acc[4][4] = {};

  const int flat0 = w * 1024 + lane * 16;
  const int flat1 = flat0 + 4096;
  const int row0 = flat0 >> 6, ke0 = (flat0 & 63) >> 1;
  const int row1 = flat1 >> 6, ke1 = (flat1 & 63) >> 1;

#define GSTAGE(bb_, k0_)                                                                       \
  do {                                                                                         \
    __builtin_amdgcn_global_load_lds(GPTR(A + (size_t)(m0 + row0) * K + (k0_) + ke0),          \
                                     SPTR(smem + (bb_)*16384 + flat0), 16, 0, 0);              \
    __builtin_amdgcn_global_load_lds(GPTR(A + (size_t)(m0 + row1) * K + (k0_) + ke1),          \
                                     SPTR(smem + (bb_)*16384 + flat1), 16, 0, 0);              \
    __builtin_amdgcn_global_load_lds(GPTR(Bt + (size_t)(n0 + row0) * K + (k0_) + ke0),         \
                                     SPTR(smem + (bb_)*16384 + 8192 + flat0), 16, 0, 0);       \
    __builtin_amdgcn_global_load_lds(GPTR(Bt + (size_t)(n0 + row1) * K + (k0_) + ke1),         \
                                     SPTR(smem + (bb_)*16384 + 8192 + flat1), 16, 0, 0);       \
  } while (0)

  GSTAGE(0, 0);
  GSTAGE(1, 32);
  const int nIt = K >> 5;  // 32
  int bi = 0, b2 = 2;
  for (int it = 0; it < nIt; ++it) {
    if (it < nIt - 1) {
      asm volatile("s_waitcnt vmcnt(4)" ::: "memory");
    } else {
      asm volatile("s_waitcnt vmcnt(0)" ::: "memory");
    }
    __builtin_amdgcn_s_barrier();
    if (it + 2 < nIt) GSTAGE(b2, (it + 2) << 5);
    const bf16* As = (const bf16*)(smem + bi * 16384);
    const bf16* Bs = (const bf16*)(smem + bi * 16384 + 8192);
    bf16x8 af[4], bfv[4];
#pragma unroll
    for (int i = 0; i < 4; ++i) {
      af[i] = *(const bf16x8*)(As + (wr * 64 + i * 16 + l15) * 32 + lhi * 8);
      bfv[i] = *(const bf16x8*)(Bs + (wc * 64 + i * 16 + l15) * 32 + lhi * 8);
    }
    __builtin_amdgcn_s_setprio(1);
#pragma unroll
    for (int i = 0; i < 4; ++i)
#pragma unroll
      for (int j = 0; j < 4; ++j) acc[i][j] = mfma16(af[i], bfv[j], acc[i][j]);
    __builtin_amdgcn_s_setprio(0);
    bi = (bi == 2) ? 0 : bi + 1;
    b2 = (b2 == 2) ? 0 : b2 + 1;
  }
#undef GSTAGE

  __syncthreads();  // k-loop LDS reads done before overlay
  const int part = n0 >> 10;  // 0=q, 1=k, 2=v
  const int b = m0 >> 11;     // tiles never straddle the batch boundary

  if (part < 2) {
    bf16* Cs = (bf16*)smem;  // [128][128]
#pragma unroll
    for (int i = 0; i < 4; ++i)
#pragma unroll
      for (int j = 0; j < 4; ++j) {
        int row = wr * 64 + i * 16 + lhi * 4;
        int col = wc * 64 + j * 16 + l15;
#pragma unroll
        for (int r = 0; r < 4; ++r) Cs[(row + r) * 128 + col] = tobf(acc[i][j][r]);
      }
    __syncthreads();
    bf16* dst = part == 0 ? Qr : Kr;
#pragma unroll
    for (int inst = 0; inst < 8; ++inst) {
      int flat = inst * 4096 + tid * 16;
      int row = flat >> 8, c0 = (flat & 255) >> 1;  // c0: multiple of 8
      int n = (m0 + row) & 2047;
      int gc = (n0 & 1023) + c0;
      int h = gc >> 6, d0 = gc & 63;
      u32x4 v = *(const u32x4*)(smem + flat);
      const float* cp = cs + (((n << 5) + (d0 >> 1)) << 1);
      f32x4 csA = *(const f32x4*)cp;        // c0,s0,c1,s1
      f32x4 csB = *(const f32x4*)(cp + 4);  // c2,s2,c3,s3
      u32x4 ow;
#pragma unroll
      for (int j = 0; j < 4; ++j) {
        float cc = (j == 0) ? csA[0] : (j == 1) ? csA[2] : (j == 2) ? csB[0] : csB[2];
        float sn = (j == 0) ? csA[1] : (j == 1) ? csA[3] : (j == 2) ? csB[1] : csB[3];
        u32 pw = v[j];
        u32 tl = pw << 16, th = pw & 0xffff0000u;
        float a0, a1;
        __builtin_memcpy(&a0, &tl, 4);
        __builtin_memcpy(&a1, &th, 4);
        bf16 o0 = tobf(a0 * cc - a1 * sn);
        bf16 o1 = tobf(a1 * cc + a0 * sn);
        unsigned short u0, u1;
        __builtin_memcpy(&u0, &o0, 2);
        __builtin_memcpy(&u1, &o1, 2);
        ow[j] = (u32)u0 | ((u32)u1 << 16);
      }
      *(u32x4*)(dst + (((size_t)(b * 16 + h) * 2048 + n) << 6) + d0) = ow;
    }
  } else {
    // v: transposed + chunk-XOR-swizzled staging, then coalesced rows out
#pragma unroll
    for (int i = 0; i < 4; ++i)
#pragma unroll
      for (int j = 0; j < 4; ++j) {
        int col = wc * 64 + j * 16 + l15;  // head-dim (tile-local row of Vt)
#pragma unroll
        for (int r = 0; r < 4; ++r) {
          int row = wr * 64 + i * 16 + lhi * 4 + r;  // token
          int byte = (col << 8) + ((((row >> 3) ^ (col & 7)) << 4) | ((row & 7) << 1));
          *(bf16*)(smem + byte) = tobf(acc[i][j][r]);
        }
      }
    __syncthreads();
#pragma unroll
    for (int inst = 0; inst < 8; ++inst) {
      int flat = inst * 4096 + tid * 16;
      int c = flat >> 8;               // head-dim row
      int rr0 = (flat & 255) >> 1;     // token start, multiple of 8
      u32x4 vv = *(const u32x4*)(smem + (c << 8) + ((((rr0 >> 3) ^ (c & 7)) << 4)));
      int gc = (n0 & 1023) + c;
      int h = gc >> 6, dd = gc & 63;
      *(u32x4*)(Vt + (((size_t)(b * 16 + h) * 64 + dd) << 11) + (m0 & 2047) + rr0) = vv;
    }
  }
}

// ---------------- Flash attention (split-K, 8 waves, counted-vmcnt pipeline) --
// Round-9 structure + VALU trims: (1) P half-exchange via permlane32_swap --
// swap(P32[x0],P32[x0+2]) yields (w0,w2) for BOTH lane-halves directly (no
// shfl, no selects); (2) ssum via v_dot2_f32_bf16 into 4 parallel chains
// (replaces unpack+tree; same bf16-rounded values, cancellation preserved).
__global__ __launch_bounds__(512, 4) void k_attn(const bf16* __restrict__ Qr,
                                                 const bf16* __restrict__ Kr,
                                                 const bf16* __restrict__ Vt,
                                                 bf16* __restrict__ AO) {
  __shared__ __attribute__((aligned(16))) char lds[2][40960];
  int wg = blockIdx.x;
  int work = (wg & 7) * 64 + (wg >> 3);
  int qc = work & 15, h = (work >> 4) & 15, b = work >> 8;
  int tid = threadIdx.x;
  int wv = tid >> 6, lane = tid & 63;
  int pipe = wv >> 2, wsub = wv & 3;
  int l31 = lane & 31, h5 = lane >> 5;
  int q0 = qc * 128 + wsub * 32;
  int kbase = pipe << 10;
  const bf16* Qb = Qr + ((size_t)(b * NH + h)) * SEQ * 64;
  const bf16* Kb = Kr + ((size_t)(b * NH + h)) * SEQ * 64;
  const bf16* Vb = Vt + ((size_t)(b * NH + h)) * 64 * SEQ;
  char* pb = lds[pipe];

  int ptid = tid & 255;
  int sf0 = ptid * 16, sf1 = 4096 + ptid * 16;
  int sr0 = sf0 >> 7, sr1 = sf1 >> 7;
  int sc0 = (sf0 & 127) ^ ((sr0 & 7) << 4);
  int sc1 = (sf1 & 127) ^ ((sr1 & 7) << 4);
  size_t kgb0 = (size_t)sr0 * 64 + (sc0 >> 1), kgb1 = (size_t)sr1 * 64 + (sc1 >> 1);
  size_t vgb0 = (size_t)sr0 * SEQ + (sc0 >> 1), vgb1 = (size_t)sr1 * SEQ + (sc1 >> 1);

#define STAGE_K(bi_, kb_)                                                                     \
  do {                                                                                        \
    size_t ko_ = (size_t)(kbase + (kb_));                                                     \
    char* bb_ = pb + (bi_)*8192;                                                              \
    __builtin_amdgcn_global_load_lds(GPTR(Kb + ko_ * 64 + kgb0), SPTR(bb_ + sf0), 16, 0, 0);  \
    __builtin_amdgcn_global_load_lds(GPTR(Kb + ko_ * 64 + kgb1), SPTR(bb_ + sf1), 16, 0, 0);  \
  } while (0)
#define STAGE_V(bi_, kb_)                                                                     \
  do {                                                                                        \
    size_t ko_ = (size_t)(kbase + (kb_));                                                     \
    char* bb_ = pb + 24576 + (bi_)*8192;                                                      \
    __builtin_amdgcn_global_load_lds(GPTR(Vb + ko_ + vgb0), SPTR(bb_ + sf0), 16, 0, 0);       \
    __builtin_amdgcn_global_load_lds(GPTR(Vb + ko_ + vgb1), SPTR(bb_ + sf1), 16, 0, 0);       \
  } while (0)

  bf16x8 qf[4];
#pragma unroll
  for (int s = 0; s < 4; ++s) qf[s] = *(const bf16x8*)(Qb + (q0 + l31) * 64 + s * 16 + h5 * 8);

  f32x16 acc0 = {}, acc1 = {};
#if HAVE_DOT2
  float sacc0 = 0.f, sacc1 = 0.f, sacc2 = 0.f, sacc3 = 0.f;
  const bf16x2 ones2 = {(bf16)1.0f, (bf16)1.0f};
#else
  float ssum_run = 0.f;
#endif
  const float sc = 0.125f * 1.44269504f;
  const float FOFF = 8.0f;
  const int sw = (l31 & 7) << 4;
  const int cbase = h5 * 16;

  STAGE_K(0, 0);
  STAGE_V(0, 0);
  STAGE_K(1, 64);

  constexpr int NT = (SEQ / 2) / 64;
  int kc = 0, kc2 = 2;
  for (int t = 0; t < NT; ++t) {
    if (t < NT - 1) {
      asm volatile("s_waitcnt vmcnt(2)" ::: "memory");
    } else {
      asm volatile("s_waitcnt vmcnt(0)" ::: "memory");
    }
    __builtin_amdgcn_s_barrier();
    if (t + 1 < NT) STAGE_V((t + 1) & 1, (t + 1) * 64);
    if (t + 2 < NT) STAGE_K(kc2, (t + 2) * 64);
    char* cbK = pb + kc * 8192;
    char* cbV = pb + 24576 + (t & 1) * 8192;
    kc = (kc == 2) ? 0 : kc + 1;
    kc2 = (kc2 == 2) ? 0 : kc2 + 1;

    f32x16 st0 = {}, st1 = {};
    __builtin_amdgcn_s_setprio(1);
#pragma unroll
    for (int s = 0; s < 4; ++s) {
      bf16x8 kf0 = *(const bf16x8*)(cbK + l31 * 128 + ((s * 32 + cbase) ^ sw));
      bf16x8 kf1 = *(const bf16x8*)(cbK + 4096 + l31 * 128 + ((s * 32 + cbase) ^ sw));
      st0 = mfma32(kf0, qf[s], st0);
      st1 = mfma32(kf1, qf[s], st1);
    }
    __builtin_amdgcn_s_setprio(0);

    float p[32];
#pragma unroll
    for (int r = 0; r < 16; ++r) p[r] = __builtin_amdgcn_exp2f(fmaf(st0[r], sc, -FOFF));
#pragma unroll
    for (int r = 0; r < 16; ++r) p[16 + r] = __builtin_amdgcn_exp2f(fmaf(st1[r], sc, -FOFF));

    u32 P32[16];
#pragma unroll
    for (int i = 0; i < 16; ++i) {
      bf16 lo = tobf(p[2 * i]), hi = tobf(p[2 * i + 1]);
      unsigned short ul, uh;
      __builtin_memcpy(&ul, &lo, 2);
      __builtin_memcpy(&uh, &hi, 2);
      P32[i] = (u32)ul | ((u32)uh << 16);
    }

#if HAVE_DOT2
    // ssum via matrix of bf16 dot2s: same bf16-rounded values, 4 chains
#pragma unroll
    for (int i = 0; i < 16; i += 4) {
      sacc0 = __builtin_amdgcn_fdot2_f32_bf16(__builtin_bit_cast(bf16x2, P32[i]), ones2, sacc0, false);
      sacc1 = __builtin_amdgcn_fdot2_f32_bf16(__builtin_bit_cast(bf16x2, P32[i + 1]), ones2, sacc1, false);
      sacc2 = __builtin_amdgcn_fdot2_f32_bf16(__builtin_bit_cast(bf16x2, P32[i + 2]), ones2, sacc2, false);
      sacc3 = __builtin_amdgcn_fdot2_f32_bf16(__builtin_bit_cast(bf16x2, P32[i + 3]), ones2, sacc3, false);
    }
#else
    {
      float sm[16];
#pragma unroll
      for (int i = 0; i < 16; ++i) {
        u32 ulo = P32[i] << 16, uhi = P32[i] & 0xffff0000u;
        float flo, fhi;
        __builtin_memcpy(&flo, &ulo, 4);
        __builtin_memcpy(&fhi, &uhi, 4);
        sm[i] = flo + fhi;
      }
#pragma unroll
      for (int off = 8; off > 0; off >>= 1)
#pragma unroll
        for (int r = 0; r < off; ++r) sm[r] += sm[r + off];
      ssum_run += sm[0];
    }
#endif

#if !HAVE_PLSWAP
    const int evens[8] = {0, 1, 4, 5, 8, 9, 12, 13};
    const int odds[8] = {2, 3, 6, 7, 10, 11, 14, 15};
    u32 recv[8];
#pragma unroll
    for (int j = 0; j < 8; ++j) {
      u32 sv = h5 ? P32[evens[j]] : P32[odds[j]];
      recv[j] = (u32)__shfl_xor((int)sv, 32, 64);
    }
#endif

    __builtin_amdgcn_s_setprio(1);
#pragma unroll
    for (int s2 = 0; s2 < 4; ++s2) {
      int x0 = ((s2 >> 1) << 3) + ((s2 & 1) << 2);  // 0,4,8,12
#if HAVE_PLSWAP
      // swap(a,b): new_a={a.lo, b.lo}, new_b={a.hi, b.hi} (lane-positional)
      // -> (w0,w2) from (P32[x0],P32[x0+2]); (w1,w3) from (P32[x0+1],P32[x0+3])
      u32x2 r02 = __builtin_amdgcn_permlane32_swap(P32[x0], P32[x0 + 2], false, false);
      u32x2 r13 = __builtin_amdgcn_permlane32_swap(P32[x0 + 1], P32[x0 + 3], false, false);
      u32x4 wv4 = {r02.x, r13.x, r02.y, r13.y};
#else
      u32 w0 = h5 ? recv[2 * s2] : P32[x0];
      u32 w1 = h5 ? recv[2 * s2 + 1] : P32[x0 + 1];
      u32 w2 = h5 ? P32[x0 + 2] : recv[2 * s2];
      u32 w3 = h5 ? P32[x0 + 3] : recv[2 * s2 + 1];
      u32x4 wv4 = {w0, w1, w2, w3};
#endif
      bf16x8 pfr = __builtin_bit_cast(bf16x8, wv4);
      bf16x8 vf0 = *(const bf16x8*)(cbV + l31 * 128 + ((s2 * 32 + cbase) ^ sw));
      bf16x8 vf1 = *(const bf16x8*)(cbV + 4096 + l31 * 128 + ((s2 * 32 + cbase) ^ sw));
      acc0 = mfma32(vf0, pfr, acc0);
      acc1 = mfma32(vf1, pfr, acc1);
    }
    __builtin_amdgcn_s_setprio(0);
  }

#if HAVE_DOT2
  float ssum = (sacc0 + sacc1) + (sacc2 + sacc3);
#else
  float ssum = ssum_run;
#endif

  __syncthreads();
  float* cacc = (float*)&lds[0][0];
  float* csum = (float*)(&lds[0][0] + 36864);
  int slot = (wsub * 64 + lane) * 36;
  if (pipe == 1) {
#pragma unroll
    for (int r = 0; r < 16; r += 4) {
      *(f32x4*)(cacc + slot + r) = f32x4{acc0[r], acc0[r + 1], acc0[r + 2], acc0[r + 3]};
      *(f32x4*)(cacc + slot + 16 + r) = f32x4{acc1[r], acc1[r + 1], acc1[r + 2], acc1[r + 3]};
    }
    csum[wsub * 64 + lane] = ssum;
  }
  __syncthreads();
  if (pipe == 0) {
#pragma unroll
    for (int r = 0; r < 16; r += 4) {
      f32x4 v0 = *(const f32x4*)(cacc + slot + r);
      f32x4 v1 = *(const f32x4*)(cacc + slot + 16 + r);
#pragma unroll
      for (int j = 0; j < 4; ++j) { acc0[r + j] += v0[j]; acc1[r + j] += v1[j]; }
    }
    ssum += csum[wsub * 64 + lane];
    ssum += __shfl_xor(ssum, 32, 64);
    float inv = 1.0f / ssum;
    size_t tok = (size_t)(b * SEQ + q0 + l31);
#pragma unroll
    for (int a = 0; a < 4; ++a) {
      bf16x4 ov0, ov1;
#pragma unroll
      for (int j = 0; j < 4; ++j) {
        ov0[j] = tobf(acc0[4 * a + j] * inv);
        ov1[j] = tobf(acc1[4 * a + j] * inv);
      }
      *(bf16x4*)(AO + tok * (NH * HD) + h * 64 + 8 * a + 4 * h5) = ov0;
      *(bf16x4*)(AO + tok * (NH * HD) + h * 64 + 32 + 8 * a + 4 * h5) = ov1;
    }
  }
#undef STAGE_K
#undef STAGE_V
}

// ---------------- launcher ----------------

extern "C" void kernel_launch(void* const* d_in, const int* in_sizes, int n_in,
                              void* d_out, int out_size, void* d_ws, size_t ws_size,
                              hipStream_t stream) {
  const float* hs = (const float*)d_in[0];
  const float* wqkv = (const float*)d_in[1];
  const float* wout = (const float*)d_in[2];
  const float* bout = (const float*)d_in[3];
  char* ws = (char*)d_ws;
  bf16* Xb = (bf16*)(ws + OXB);
  bf16* Wqkt = (bf16*)(ws + OWQ);
  bf16* Woutt = (bf16*)(ws + OWO);
  float* cs = (float*)(ws + OCS);
  bf16* Qr = (bf16*)(ws + OQR);
  bf16* Kr = (bf16*)(ws + OKR);
  bf16* Vt = (bf16*)(ws + OVT);
  bf16* AO = (bf16*)(ws + OAO);

  k_prep<<<8448, 256, 0, stream>>>(hs, wqkv, wout, cs, Xb, Wqkt, Woutt);
  k_gemm1f<<<(MTOK / 128) * (QKV3 / 128), 256, 0, stream>>>(Xb, Wqkt, cs, Qr, Kr, Vt);
  k_attn<<<BATCH * NH * (SEQ / 128), 512, 0, stream>>>(Qr, Kr, Vt, AO);
  k_gemm2<<<(MTOK / 128) * (DMODEL / 128), 256, 0, stream>>>(AO, Woutt, (float*)d_out, bout, MTOK, DMODEL, DMODEL);
}

// Round 13
// 116.237 us; speedup vs baseline: 1.8817x; 1.0121x over previous
//
#include <hip/hip_runtime.h>
#include <hip/hip_bf16.h>

typedef __bf16 bf16;
typedef unsigned int u32;
typedef __attribute__((ext_vector_type(4))) float f32x4;
typedef __attribute__((ext_vector_type(16))) float f32x16;
typedef __attribute__((ext_vector_type(8))) bf16 bf16x8;
typedef __attribute__((ext_vector_type(4))) bf16 bf16x4;
typedef __attribute__((ext_vector_type(2))) bf16 bf16x2;
typedef __attribute__((ext_vector_type(4))) u32 u32x4;
typedef __attribute__((ext_vector_type(2))) u32 u32x2;

#define GPTR(p) ((const __attribute__((address_space(1))) u32*)(p))
#define SPTR(p) ((__attribute__((address_space(3))) u32*)(p))

#if __has_builtin(__builtin_amdgcn_permlane32_swap)
#define HAVE_PLSWAP 1
#else
#define HAVE_PLSWAP 0
#endif
#if __has_builtin(__builtin_amdgcn_fdot2_f32_bf16)
#define HAVE_DOT2 1
#else
#define HAVE_DOT2 0
#endif

// Problem constants
constexpr int BATCH = 2, SEQ = 2048, DMODEL = 1024, NH = 16, HD = 64, QKV3 = 3072;
constexpr int MTOK = BATCH * SEQ;  // 4096 tokens

// Workspace layout (bytes)
constexpr size_t OXB = 0;                                       // X bf16 [4096][1024]
constexpr size_t OWQ = OXB + (size_t)MTOK * DMODEL * 2;         // Wqkv^T bf16 [3072][1024]
constexpr size_t OWO = OWQ + (size_t)QKV3 * DMODEL * 2;         // Wout^T bf16 [1024][1024]
constexpr size_t OCS = OWO + (size_t)DMODEL * DMODEL * 2;       // cos/sin f32 [2048][32][2]
constexpr size_t OCQ = OCS + (size_t)SEQ * 32 * 8;              // (hole)
constexpr size_t OQR = OCQ + (size_t)MTOK * QKV3 * 2;           // Q roped [b][h][n][64]
constexpr size_t OKR = OQR + (size_t)BATCH * NH * SEQ * HD * 2; // K roped
constexpr size_t OVT = OKR + (size_t)BATCH * NH * SEQ * HD * 2; // V^T [b][h][64][n]
constexpr size_t OAO = OXB;                                     // attn out (aliases Xb, dead by then)

static __device__ __forceinline__ bf16 tobf(float x) { return (bf16)x; }
static __device__ __forceinline__ float tof(bf16 x) { return (float)x; }

static __device__ __forceinline__ f32x4 mfma16(bf16x8 a, bf16x8 b, f32x4 c) {
  return __builtin_amdgcn_mfma_f32_16x16x32_bf16(a, b, c, 0, 0, 0);
}
static __device__ __forceinline__ f32x16 mfma32(bf16x8 a, bf16x8 b, f32x16 c) {
  return __builtin_amdgcn_mfma_f32_32x32x16_bf16(a, b, c, 0, 0, 0);
}

// ---------------- fused prep kernel (costab | cvt | transW_qkv) ----------
// (w_out transpose moved into k_gemm1f's extra blocks -- no dependency)
__global__ void k_prep(const float* __restrict__ hs, const float* __restrict__ wqkv,
                       float* __restrict__ cs, bf16* __restrict__ Xb,
                       bf16* __restrict__ Wqkt) {
  __shared__ float tile[32][33];
  int blk = blockIdx.x, tid = threadIdx.x;
  if (blk < 256) {
    int idx = blk * 256 + tid;
    int n = idx >> 5, i = idx & 31;
    float freq = powf(10000.0f, -(float)(2 * i) / 64.0f);
    float ang = (float)n * freq;
    float s, c;
    sincosf(ang, &s, &c);
    cs[idx * 2] = c;
    cs[idx * 2 + 1] = s;
  } else if (blk < 256 + 4096) {
    int i = (blk - 256) * 256 + tid;
    float4 v = ((const float4*)hs)[i];
    bf16x4 o = {tobf(v.x), tobf(v.y), tobf(v.z), tobf(v.w)};
    ((bf16x4*)Xb)[i] = o;
  } else {
    int t = blk - 4352;  // [0, 3072)
    int n0 = (t % 96) * 32, k0 = (t / 96) * 32;
    int tx = tid & 31, ty = tid >> 5;
#pragma unroll
    for (int r = ty; r < 32; r += 8) tile[r][tx] = wqkv[(size_t)(k0 + r) * QKV3 + n0 + tx];
    __syncthreads();
#pragma unroll
    for (int r = ty; r < 32; r += 8) Wqkt[(size_t)(n0 + r) * DMODEL + k0 + tx] = tobf(tile[tx][r]);
  }
}

// LDS tile swizzle (both GEMMs): 64B rows, 4x16B slots; slot' = slot ^ ((row>>1)&3).
// Staged with pre-swizzled GLOBAL k-offset (dest linear, required by global_load_lds);
// read with the same XOR. Read-side XOR term = (l15>>1)&3 -- loop-invariant per lane.

// ---------------- GEMM2: A bf16 [M][K] x Bt bf16 [N][K] -> C f32 + bias ------

__global__ __launch_bounds__(256) void k_gemm2(const bf16* __restrict__ A, const bf16* __restrict__ Bt,
                                               float* __restrict__ C, const float* __restrict__ bias,
                                               int M, int Nn, int K) {
  __shared__ __attribute__((aligned(16))) char smem[49152];  // 3 x (As 8KB | Bs 8KB)
  const int nTn = Nn >> 7;
  int nwg = gridDim.x;
  int bid = blockIdx.x;
  int wgs = (bid & 7) * (nwg >> 3) + (bid >> 3);  // bijective XCD swizzle (nwg%8==0)
  const int m0 = (wgs / nTn) << 7;
  const int n0 = (wgs % nTn) << 7;
  const int tid = threadIdx.x;
  const int lane = tid & 63, w = tid >> 6;
  const int wr = w >> 1, wc = w & 1;
  const int l15 = lane & 15, lhi = lane >> 4;
  f32x4 acc[4][4] = {};

  const int flat0 = w * 1024 + lane * 16;  // byte offset in 8KB half-tile
  const int flat1 = flat0 + 4096;
  const int row0 = flat0 >> 6, row1 = flat1 >> 6;
  const int ke0 = (((flat0 & 63) >> 4) ^ ((row0 >> 1) & 3)) << 3;  // swizzled k-elem offset
  const int ke1 = (((flat1 & 63) >> 4) ^ ((row1 >> 1) & 3)) << 3;
  const int rsw = ((l15 >> 1) & 3) << 3;  // read-side XOR term (elements)

#define GSTAGE(bb_, k0_)                                                                       \
  do {                                                                                         \
    __builtin_amdgcn_global_load_lds(GPTR(A + (size_t)(m0 + row0) * K + (k0_) + ke0),          \
                                     SPTR(smem + (bb_)*16384 + flat0), 16, 0, 0);              \
    __builtin_amdgcn_global_load_lds(GPTR(A + (size_t)(m0 + row1) * K + (k0_) + ke1),          \
                                     SPTR(smem + (bb_)*16384 + flat1), 16, 0, 0);              \
    __builtin_amdgcn_global_load_lds(GPTR(Bt + (size_t)(n0 + row0) * K + (k0_) + ke0),         \
                                     SPTR(smem + (bb_)*16384 + 8192 + flat0), 16, 0, 0);       \
    __builtin_amdgcn_global_load_lds(GPTR(Bt + (size_t)(n0 + row1) * K + (k0_) + ke1),         \
                                     SPTR(smem + (bb_)*16384 + 8192 + flat1), 16, 0, 0);       \
  } while (0)

  GSTAGE(0, 0);
  GSTAGE(1, 32);
  const int nIt = K >> 5;
  int bi = 0, b2 = 2;
  for (int it = 0; it < nIt; ++it) {
    if (it < nIt - 1) {
      asm volatile("s_waitcnt vmcnt(4)" ::: "memory");
    } else {
      asm volatile("s_waitcnt vmcnt(0)" ::: "memory");
    }
    __builtin_amdgcn_s_barrier();
    if (it + 2 < nIt) GSTAGE(b2, (it + 2) << 5);
    const bf16* As = (const bf16*)(smem + bi * 16384);
    const bf16* Bs = (const bf16*)(smem + bi * 16384 + 8192);
    bf16x8 af[4], bfv[4];
#pragma unroll
    for (int i = 0; i < 4; ++i) {
      af[i] = *(const bf16x8*)(As + (wr * 64 + i * 16 + l15) * 32 + ((lhi << 3) ^ rsw));
      bfv[i] = *(const bf16x8*)(Bs + (wc * 64 + i * 16 + l15) * 32 + ((lhi << 3) ^ rsw));
    }
    __builtin_amdgcn_s_setprio(1);
#pragma unroll
    for (int i = 0; i < 4; ++i)
#pragma unroll
      for (int j = 0; j < 4; ++j) acc[i][j] = mfma16(af[i], bfv[j], acc[i][j]);
    __builtin_amdgcn_s_setprio(0);
    bi = (bi == 2) ? 0 : bi + 1;
    b2 = (b2 == 2) ? 0 : b2 + 1;
  }
#undef GSTAGE

  float bj[4];
#pragma unroll
  for (int j = 0; j < 4; ++j) bj[j] = bias[n0 + wc * 64 + j * 16 + l15];
#pragma unroll
  for (int i = 0; i < 4; ++i)
#pragma unroll
    for (int j = 0; j < 4; ++j) {
      int row = m0 + wr * 64 + i * 16 + lhi * 4;
      int col = n0 + wc * 64 + j * 16 + l15;
#pragma unroll
      for (int r = 0; r < 4; ++r) C[(size_t)(row + r) * Nn + col] = acc[i][j][r] + bj[j];
    }
}

// ---------------- GEMM1 fused: X x Wqkv^T -> RoPE(Q), RoPE(K), V^T ----------
// Blocks [0,768): GEMM with fused epilogue. Blocks [768,1792): w_out transpose
// tiles (independent work overlapped with the GEMM; result used by k_gemm2).

__global__ __launch_bounds__(256) void k_gemm1f(const bf16* __restrict__ A, const bf16* __restrict__ Bt,
                                                const float* __restrict__ cs,
                                                const float* __restrict__ wout, bf16* __restrict__ Woutt,
                                                bf16* __restrict__ Qr, bf16* __restrict__ Kr,
                                                bf16* __restrict__ Vt) {
  constexpr int K = DMODEL, Nn = QKV3;
  constexpr int NG = (MTOK / 128) * (QKV3 / 128);  // 768 GEMM blocks
  __shared__ __attribute__((aligned(16))) char smem[49152];
  int bid = blockIdx.x;
  const int tid = threadIdx.x;

  if (bid >= NG) {
    // ---- w_out transpose: f32 [1024][1024] -> bf16 [1024][1024]^T ----
    float* tile = (float*)smem;  // [32][33]
    int t = bid - NG;            // [0, 1024)
    int n0 = (t & 31) * 32, k0 = (t >> 5) * 32;
    int tx = tid & 31, ty = tid >> 5;
#pragma unroll
    for (int r = ty; r < 32; r += 8) tile[r * 33 + tx] = wout[(size_t)(k0 + r) * DMODEL + n0 + tx];
    __syncthreads();
#pragma unroll
    for (int r = ty; r < 32; r += 8) Woutt[(size_t)(n0 + r) * DMODEL + k0 + tx] = tobf(tile[tx * 33 + r]);
    return;
  }

  const int nTn = Nn >> 7;  // 24
  int wgs = (bid & 7) * (NG >> 3) + (bid >> 3);  // swizzle within the 768 GEMM blocks
  const int m0 = (wgs / nTn) << 7;
  const int n0 = (wgs % nTn) << 7;
  const int lane = tid & 63, w = tid >> 6;
  const int wr = w >> 1, wc = w & 1;
  const int l15 = lane & 15, lhi = lane >> 4;
  f32x4 acc[4][4] = {};

  const int flat0 = w * 1024 + lane * 16;
  const int flat1 = flat0 + 4096;
  const int row0 = flat0 >> 6, row1 = flat1 >> 6;
  const int ke0 = (((flat0 & 63) >> 4) ^ ((row0 >> 1) & 3)) << 3;
  const int ke1 = (((flat1 & 63) >> 4) ^ ((row1 >> 1) & 3)) << 3;
  const int rsw = ((l15 >> 1) & 3) << 3;

#define GSTAGE(bb_, k0_)                                                                       \
  do {                                                                                         \
    __builtin_amdgcn_global_load_lds(GPTR(A + (size_t)(m0 + row0) * K + (k0_) + ke0),          \
                                     SPTR(smem + (bb_)*16384 + flat0), 16, 0, 0);              \
    __builtin_amdgcn_global_load_lds(GPTR(A + (size_t)(m0 + row1) * K + (k0_) + ke1),          \
                                     SPTR(smem + (bb_)*16384 + flat1), 16, 0, 0);              \
    __builtin_amdgcn_global_load_lds(GPTR(Bt + (size_t)(n0 + row0) * K + (k0_) + ke0),         \
                                     SPTR(smem + (bb_)*16384 + 8192 + flat0), 16, 0, 0);       \
    __builtin_amdgcn_global_load_lds(GPTR(Bt + (size_t)(n0 + row1) * K + (k0_) + ke1),         \
                                     SPTR(smem + (bb_)*16384 + 8192 + flat1), 16, 0, 0);       \
  } while (0)

  GSTAGE(0, 0);
  GSTAGE(1, 32);
  const int nIt = K >> 5;  // 32
  int bi = 0, b2 = 2;
  for (int it = 0; it < nIt; ++it) {
    if (it < nIt - 1) {
      asm volatile("s_waitcnt vmcnt(4)" ::: "memory");
    } else {
      asm volatile("s_waitcnt vmcnt(0)" ::: "memory");
    }
    __builtin_amdgcn_s_barrier();
    if (it + 2 < nIt) GSTAGE(b2, (it + 2) << 5);
    const bf16* As = (const bf16*)(smem + bi * 16384);
    const bf16* Bs = (const bf16*)(smem + bi * 16384 + 8192);
    bf16x8 af[4], bfv[4];
#pragma unroll
    for (int i = 0; i < 4; ++i) {
      af[i] = *(const bf16x8*)(As + (wr * 64 + i * 16 + l15) * 32 + ((lhi << 3) ^ rsw));
      bfv[i] = *(const bf16x8*)(Bs + (wc * 64 + i * 16 + l15) * 32 + ((lhi << 3) ^ rsw));
    }
    __builtin_amdgcn_s_setprio(1);
#pragma unroll
    for (int i = 0; i < 4; ++i)
#pragma unroll
      for (int j = 0; j < 4; ++j) acc[i][j] = mfma16(af[i], bfv[j], acc[i][j]);
    __builtin_amdgcn_s_setprio(0);
    bi = (bi == 2) ? 0 : bi + 1;
    b2 = (b2 == 2) ? 0 : b2 + 1;
  }
#undef GSTAGE

  __syncthreads();  // k-loop LDS reads done before overlay
  const int part = n0 >> 10;  // 0=q, 1=k, 2=v
  const int b = m0 >> 11;     // tiles never straddle the batch boundary

  if (part < 2) {
    bf16* Cs = (bf16*)smem;  // [128][128]
#pragma unroll
    for (int i = 0; i < 4; ++i)
#pragma unroll
      for (int j = 0; j < 4; ++j) {
        int row = wr * 64 + i * 16 + lhi * 4;
        int col = wc * 64 + j * 16 + l15;
#pragma unroll
        for (int r = 0; r < 4; ++r) Cs[(row + r) * 128 + col] = tobf(acc[i][j][r]);
      }
    __syncthreads();
    bf16* dst = part == 0 ? Qr : Kr;
#pragma unroll
    for (int inst = 0; inst < 8; ++inst) {
      int flat = inst * 4096 + tid * 16;
      int row = flat >> 8, c0 = (flat & 255) >> 1;  // c0: multiple of 8
      int n = (m0 + row) & 2047;
      int gc = (n0 & 1023) + c0;
      int h = gc >> 6, d0 = gc & 63;
      u32x4 v = *(const u32x4*)(smem + flat);
      const float* cp = cs + (((n << 5) + (d0 >> 1)) << 1);
      f32x4 csA = *(const f32x4*)cp;        // c0,s0,c1,s1
      f32x4 csB = *(const f32x4*)(cp + 4);  // c2,s2,c3,s3
      u32x4 ow;
#pragma unroll
      for (int j = 0; j < 4; ++j) {
        float cc = (j == 0) ? csA[0] : (j == 1) ? csA[2] : (j == 2) ? csB[0] : csB[2];
        float sn = (j == 0) ? csA[1] : (j == 1) ? csA[3] : (j == 2) ? csB[1] : csB[3];
        u32 pw = v[j];
        u32 tl = pw << 16, th = pw & 0xffff0000u;
        float a0, a1;
        __builtin_memcpy(&a0, &tl, 4);
        __builtin_memcpy(&a1, &th, 4);
        bf16 o0 = tobf(a0 * cc - a1 * sn);
        bf16 o1 = tobf(a1 * cc + a0 * sn);
        unsigned short u0, u1;
        __builtin_memcpy(&u0, &o0, 2);
        __builtin_memcpy(&u1, &o1, 2);
        ow[j] = (u32)u0 | ((u32)u1 << 16);
      }
      *(u32x4*)(dst + (((size_t)(b * 16 + h) * 2048 + n) << 6) + d0) = ow;
    }
  } else {
    // v: transposed + chunk-XOR-swizzled staging, then coalesced rows out
#pragma unroll
    for (int i = 0; i < 4; ++i)
#pragma unroll
      for (int j = 0; j < 4; ++j) {
        int col = wc * 64 + j * 16 + l15;  // head-dim (tile-local row of Vt)
#pragma unroll
        for (int r = 0; r < 4; ++r) {
          int row = wr * 64 + i * 16 + lhi * 4 + r;  // token
          int byte = (col << 8) + ((((row >> 3) ^ (col & 7)) << 4) | ((row & 7) << 1));
          *(bf16*)(smem + byte) = tobf(acc[i][j][r]);
        }
      }
    __syncthreads();
#pragma unroll
    for (int inst = 0; inst < 8; ++inst) {
      int flat = inst * 4096 + tid * 16;
      int c = flat >> 8;               // head-dim row
      int rr0 = (flat & 255) >> 1;     // token start, multiple of 8
      u32x4 vv = *(const u32x4*)(smem + (c << 8) + ((((rr0 >> 3) ^ (c & 7)) << 4)));
      int gc = (n0 & 1023) + c;
      int h = gc >> 6, dd = gc & 63;
      *(u32x4*)(Vt + (((size_t)(b * 16 + h) * 64 + dd) << 11) + (m0 & 2047) + rr0) = vv;
    }
  }
}

// ---------------- Flash attention (unchanged from round 12) ----------------
__global__ __launch_bounds__(512, 4) void k_attn(const bf16* __restrict__ Qr,
                                                 const bf16* __restrict__ Kr,
                                                 const bf16* __restrict__ Vt,
                                                 bf16* __restrict__ AO) {
  __shared__ __attribute__((aligned(16))) char lds[2][40960];
  int wg = blockIdx.x;
  int work = (wg & 7) * 64 + (wg >> 3);
  int qc = work & 15, h = (work >> 4) & 15, b = work >> 8;
  int tid = threadIdx.x;
  int wv = tid >> 6, lane = tid & 63;
  int pipe = wv >> 2, wsub = wv & 3;
  int l31 = lane & 31, h5 = lane >> 5;
  int q0 = qc * 128 + wsub * 32;
  int kbase = pipe << 10;
  const bf16* Qb = Qr + ((size_t)(b * NH + h)) * SEQ * 64;
  const bf16* Kb = Kr + ((size_t)(b * NH + h)) * SEQ * 64;
  const bf16* Vb = Vt + ((size_t)(b * NH + h)) * 64 * SEQ;
  char* pb = lds[pipe];

  int ptid = tid & 255;
  int sf0 = ptid * 16, sf1 = 4096 + ptid * 16;
  int sr0 = sf0 >> 7, sr1 = sf1 >> 7;
  int sc0 = (sf0 & 127) ^ ((sr0 & 7) << 4);
  int sc1 = (sf1 & 127) ^ ((sr1 & 7) << 4);
  size_t kgb0 = (size_t)sr0 * 64 + (sc0 >> 1), kgb1 = (size_t)sr1 * 64 + (sc1 >> 1);
  size_t vgb0 = (size_t)sr0 * SEQ + (sc0 >> 1), vgb1 = (size_t)sr1 * SEQ + (sc1 >> 1);

#define STAGE_K(bi_, kb_)                                                                     \
  do {                                                                                        \
    size_t ko_ = (size_t)(kbase + (kb_));                                                     \
    char* bb_ = pb + (bi_)*8192;                                                              \
    __builtin_amdgcn_global_load_lds(GPTR(Kb + ko_ * 64 + kgb0), SPTR(bb_ + sf0), 16, 0, 0);  \
    __builtin_amdgcn_global_load_lds(GPTR(Kb + ko_ * 64 + kgb1), SPTR(bb_ + sf1), 16, 0, 0);  \
  } while (0)
#define STAGE_V(bi_, kb_)                                                                     \
  do {                                                                                        \
    size_t ko_ = (size_t)(kbase + (kb_));                                                     \
    char* bb_ = pb + 24576 + (bi_)*8192;                                                      \
    __builtin_amdgcn_global_load_lds(GPTR(Vb + ko_ + vgb0), SPTR(bb_ + sf0), 16, 0, 0);       \
    __builtin_amdgcn_global_load_lds(GPTR(Vb + ko_ + vgb1), SPTR(bb_ + sf1), 16, 0, 0);       \
  } while (0)

  bf16x8 qf[4];
#pragma unroll
  for (int s = 0; s < 4; ++s) qf[s] = *(const bf16x8*)(Qb + (q0 + l31) * 64 + s * 16 + h5 * 8);

  f32x16 acc0 = {}, acc1 = {};
#if HAVE_DOT2
  float sacc0 = 0.f, sacc1 = 0.f, sacc2 = 0.f, sacc3 = 0.f;
  const bf16x2 ones2 = {(bf16)1.0f, (bf16)1.0f};
#else
  float ssum_run = 0.f;
#endif
  const float sc = 0.125f * 1.44269504f;
  const float FOFF = 8.0f;
  const int sw = (l31 & 7) << 4;
  const int cbase = h5 * 16;

  STAGE_K(0, 0);
  STAGE_V(0, 0);
  STAGE_K(1, 64);

  constexpr int NT = (SEQ / 2) / 64;
  int kc = 0, kc2 = 2;
  for (int t = 0; t < NT; ++t) {
    if (t < NT - 1) {
      asm volatile("s_waitcnt vmcnt(2)" ::: "memory");
    } else {
      asm volatile("s_waitcnt vmcnt(0)" ::: "memory");
    }
    __builtin_amdgcn_s_barrier();
    if (t + 1 < NT) STAGE_V((t + 1) & 1, (t + 1) * 64);
    if (t + 2 < NT) STAGE_K(kc2, (t + 2) * 64);
    char* cbK = pb + kc * 8192;
    char* cbV = pb + 24576 + (t & 1) * 8192;
    kc = (kc == 2) ? 0 : kc + 1;
    kc2 = (kc2 == 2) ? 0 : kc2 + 1;

    f32x16 st0 = {}, st1 = {};
    __builtin_amdgcn_s_setprio(1);
#pragma unroll
    for (int s = 0; s < 4; ++s) {
      bf16x8 kf0 = *(const bf16x8*)(cbK + l31 * 128 + ((s * 32 + cbase) ^ sw));
      bf16x8 kf1 = *(const bf16x8*)(cbK + 4096 + l31 * 128 + ((s * 32 + cbase) ^ sw));
      st0 = mfma32(kf0, qf[s], st0);
      st1 = mfma32(kf1, qf[s], st1);
    }
    __builtin_amdgcn_s_setprio(0);

    float p[32];
#pragma unroll
    for (int r = 0; r < 16; ++r) p[r] = __builtin_amdgcn_exp2f(fmaf(st0[r], sc, -FOFF));
#pragma unroll
    for (int r = 0; r < 16; ++r) p[16 + r] = __builtin_amdgcn_exp2f(fmaf(st1[r], sc, -FOFF));

    u32 P32[16];
#pragma unroll
    for (int i = 0; i < 16; ++i) {
      bf16 lo = tobf(p[2 * i]), hi = tobf(p[2 * i + 1]);
      unsigned short ul, uh;
      __builtin_memcpy(&ul, &lo, 2);
      __builtin_memcpy(&uh, &hi, 2);
      P32[i] = (u32)ul | ((u32)uh << 16);
    }

#if HAVE_DOT2
#pragma unroll
    for (int i = 0; i < 16; i += 4) {
      sacc0 = __builtin_amdgcn_fdot2_f32_bf16(__builtin_bit_cast(bf16x2, P32[i]), ones2, sacc0, false);
      sacc1 = __builtin_amdgcn_fdot2_f32_bf16(__builtin_bit_cast(bf16x2, P32[i + 1]), ones2, sacc1, false);
      sacc2 = __builtin_amdgcn_fdot2_f32_bf16(__builtin_bit_cast(bf16x2, P32[i + 2]), ones2, sacc2, false);
      sacc3 = __builtin_amdgcn_fdot2_f32_bf16(__builtin_bit_cast(bf16x2, P32[i + 3]), ones2, sacc3, false);
    }
#else
    {
      float sm[16];
#pragma unroll
      for (int i = 0; i < 16; ++i) {
        u32 ulo = P32[i] << 16, uhi = P32[i] & 0xffff0000u;
        float flo, fhi;
        __builtin_memcpy(&flo, &ulo, 4);
        __builtin_memcpy(&fhi, &uhi, 4);
        sm[i] = flo + fhi;
      }
#pragma unroll
      for (int off = 8; off > 0; off >>= 1)
#pragma unroll
        for (int r = 0; r < off; ++r) sm[r] += sm[r + off];
      ssum_run += sm[0];
    }
#endif

#if !HAVE_PLSWAP
    const int evens[8] = {0, 1, 4, 5, 8, 9, 12, 13};
    const int odds[8] = {2, 3, 6, 7, 10, 11, 14, 15};
    u32 recv[8];
#pragma unroll
    for (int j = 0; j < 8; ++j) {
      u32 sv = h5 ? P32[evens[j]] : P32[odds[j]];
      recv[j] = (u32)__shfl_xor((int)sv, 32, 64);
    }
#endif

    __builtin_amdgcn_s_setprio(1);
#pragma unroll
    for (int s2 = 0; s2 < 4; ++s2) {
      int x0 = ((s2 >> 1) << 3) + ((s2 & 1) << 2);  // 0,4,8,12
#if HAVE_PLSWAP
      u32x2 r02 = __builtin_amdgcn_permlane32_swap(P32[x0], P32[x0 + 2], false, false);
      u32x2 r13 = __builtin_amdgcn_permlane32_swap(P32[x0 + 1], P32[x0 + 3], false, false);
      u32x4 wv4 = {r02.x, r13.x, r02.y, r13.y};
#else
      u32 w0 = h5 ? recv[2 * s2] : P32[x0];
      u32 w1 = h5 ? recv[2 * s2 + 1] : P32[x0 + 1];
      u32 w2 = h5 ? P32[x0 + 2] : recv[2 * s2];
      u32 w3 = h5 ? P32[x0 + 3] : recv[2 * s2 + 1];
      u32x4 wv4 = {w0, w1, w2, w3};
#endif
      bf16x8 pfr = __builtin_bit_cast(bf16x8, wv4);
      bf16x8 vf0 = *(const bf16x8*)(cbV + l31 * 128 + ((s2 * 32 + cbase) ^ sw));
      bf16x8 vf1 = *(const bf16x8*)(cbV + 4096 + l31 * 128 + ((s2 * 32 + cbase) ^ sw));
      acc0 = mfma32(vf0, pfr, acc0);
      acc1 = mfma32(vf1, pfr, acc1);
    }
    __builtin_amdgcn_s_setprio(0);
  }

#if HAVE_DOT2
  float ssum = (sacc0 + sacc1) + (sacc2 + sacc3);
#else
  float ssum = ssum_run;
#endif

  __syncthreads();
  float* cacc = (float*)&lds[0][0];
  float* csum = (float*)(&lds[0][0] + 36864);
  int slot = (wsub * 64 + lane) * 36;
  if (pipe == 1) {
#pragma unroll
    for (int r = 0; r < 16; r += 4) {
      *(f32x4*)(cacc + slot + r) = f32x4{acc0[r], acc0[r + 1], acc0[r + 2], acc0[r + 3]};
      *(f32x4*)(cacc + slot + 16 + r) = f32x4{acc1[r], acc1[r + 1], acc1[r + 2], acc1[r + 3]};
    }
    csum[wsub * 64 + lane] = ssum;
  }
  __syncthreads();
  if (pipe == 0) {
#pragma unroll
    for (int r = 0; r < 16; r += 4) {
      f32x4 v0 = *(const f32x4*)(cacc + slot + r);
      f32x4 v1 = *(const f32x4*)(cacc + slot + 16 + r);
#pragma unroll
      for (int j = 0; j < 4; ++j) { acc0[r + j] += v0[j]; acc1[r + j] += v1[j]; }
    }
    ssum += csum[wsub * 64 + lane];
    ssum += __shfl_xor(ssum, 32, 64);
    float inv = 1.0f / ssum;
    size_t tok = (size_t)(b * SEQ + q0 + l31);
#pragma unroll
    for (int a = 0; a < 4; ++a) {
      bf16x4 ov0, ov1;
#pragma unroll
      for (int j = 0; j < 4; ++j) {
        ov0[j] = tobf(acc0[4 * a + j] * inv);
        ov1[j] = tobf(acc1[4 * a + j] * inv);
      }
      *(bf16x4*)(AO + tok * (NH * HD) + h * 64 + 8 * a + 4 * h5) = ov0;
      *(bf16x4*)(AO + tok * (NH * HD) + h * 64 + 32 + 8 * a + 4 * h5) = ov1;
    }
  }
#undef STAGE_K
#undef STAGE_V
}

// ---------------- launcher ----------------

extern "C" void kernel_launch(void* const* d_in, const int* in_sizes, int n_in,
                              void* d_out, int out_size, void* d_ws, size_t ws_size,
                              hipStream_t stream) {
  const float* hs = (const float*)d_in[0];
  const float* wqkv = (const float*)d_in[1];
  const float* wout = (const float*)d_in[2];
  const float* bout = (const float*)d_in[3];
  char* ws = (char*)d_ws;
  bf16* Xb = (bf16*)(ws + OXB);
  bf16* Wqkt = (bf16*)(ws + OWQ);
  bf16* Woutt = (bf16*)(ws + OWO);
  float* cs = (float*)(ws + OCS);
  bf16* Qr = (bf16*)(ws + OQR);
  bf16* Kr = (bf16*)(ws + OKR);
  bf16* Vt = (bf16*)(ws + OVT);
  bf16* AO = (bf16*)(ws + OAO);

  k_prep<<<7424, 256, 0, stream>>>(hs, wqkv, cs, Xb, Wqkt);
  k_gemm1f<<<(MTOK / 128) * (QKV3 / 128) + 1024, 256, 0, stream>>>(Xb, Wqkt, cs, wout, Woutt, Qr, Kr, Vt);
  k_attn<<<BATCH * NH * (SEQ / 128), 512, 0, stream>>>(Qr, Kr, Vt, AO);
  k_gemm2<<<(MTOK / 128) * (DMODEL / 128), 256, 0, stream>>>(AO, Woutt, (float*)d_out, bout, MTOK, DMODEL, DMODEL);
}

// Round 15
// 115.539 us; speedup vs baseline: 1.8930x; 1.0060x over previous
//
#include <hip/hip_runtime.h>
#include <hip/hip_bf16.h>

typedef __bf16 bf16;
typedef unsigned int u32;
typedef __attribute__((ext_vector_type(4))) float f32x4;
typedef __attribute__((ext_vector_type(16))) float f32x16;
typedef __attribute__((ext_vector_type(8))) bf16 bf16x8;
typedef __attribute__((ext_vector_type(4))) bf16 bf16x4;
typedef __attribute__((ext_vector_type(2))) bf16 bf16x2;
typedef __attribute__((ext_vector_type(4))) u32 u32x4;
typedef __attribute__((ext_vector_type(2))) u32 u32x2;

#define GPTR(p) ((const __attribute__((address_space(1))) u32*)(p))
#define SPTR(p) ((__attribute__((address_space(3))) u32*)(p))

#if __has_builtin(__builtin_amdgcn_permlane32_swap)
#define HAVE_PLSWAP 1
#else
#define HAVE_PLSWAP 0
#endif
#if __has_builtin(__builtin_amdgcn_fdot2_f32_bf16)
#define HAVE_DOT2 1
#else
#define HAVE_DOT2 0
#endif

// Problem constants
constexpr int BATCH = 2, SEQ = 2048, DMODEL = 1024, NH = 16, HD = 64, QKV3 = 3072;
constexpr int MTOK = BATCH * SEQ;  // 4096 tokens

// Workspace layout (bytes)
constexpr size_t OXB = 0;                                       // X bf16 [4096][1024]
constexpr size_t OWQ = OXB + (size_t)MTOK * DMODEL * 2;         // Wqkv^T bf16 [3072][1024]
constexpr size_t OWO = OWQ + (size_t)QKV3 * DMODEL * 2;         // Wout^T bf16 [1024][1024]
constexpr size_t OCS = OWO + (size_t)DMODEL * DMODEL * 2;       // cos/sin f32 [2048][32][2]
constexpr size_t OCQ = OCS + (size_t)SEQ * 32 * 8;              // (hole)
constexpr size_t OQR = OCQ + (size_t)MTOK * QKV3 * 2;           // Q roped [b][h][n][64]
constexpr size_t OKR = OQR + (size_t)BATCH * NH * SEQ * HD * 2; // K roped
constexpr size_t OVT = OKR + (size_t)BATCH * NH * SEQ * HD * 2; // V^T [b][h][64][n]
constexpr size_t OAO = OXB;                                     // attn out (aliases Xb, dead by then)

static __device__ __forceinline__ bf16 tobf(float x) { return (bf16)x; }
static __device__ __forceinline__ float tof(bf16 x) { return (float)x; }

static __device__ __forceinline__ f32x4 mfma16(bf16x8 a, bf16x8 b, f32x4 c) {
  return __builtin_amdgcn_mfma_f32_16x16x32_bf16(a, b, c, 0, 0, 0);
}
static __device__ __forceinline__ f32x16 mfma32(bf16x8 a, bf16x8 b, f32x16 c) {
  return __builtin_amdgcn_mfma_f32_32x32x16_bf16(a, b, c, 0, 0, 0);
}

// ---------------- fused prep kernel (costab | cvt | transW_qkv) ----------
__global__ void k_prep(const float* __restrict__ hs, const float* __restrict__ wqkv,
                       float* __restrict__ cs, bf16* __restrict__ Xb,
                       bf16* __restrict__ Wqkt) {
  __shared__ float tile[32][33];
  int blk = blockIdx.x, tid = threadIdx.x;
  if (blk < 256) {
    int idx = blk * 256 + tid;
    int n = idx >> 5, i = idx & 31;
    float freq = powf(10000.0f, -(float)(2 * i) / 64.0f);
    float ang = (float)n * freq;
    float s, c;
    sincosf(ang, &s, &c);
    cs[idx * 2] = c;
    cs[idx * 2 + 1] = s;
  } else if (blk < 256 + 4096) {
    int i = (blk - 256) * 256 + tid;
    float4 v = ((const float4*)hs)[i];
    bf16x4 o = {tobf(v.x), tobf(v.y), tobf(v.z), tobf(v.w)};
    ((bf16x4*)Xb)[i] = o;
  } else {
    int t = blk - 4352;  // [0, 3072)
    int n0 = (t % 96) * 32, k0 = (t / 96) * 32;
    int tx = tid & 31, ty = tid >> 5;
#pragma unroll
    for (int r = ty; r < 32; r += 8) tile[r][tx] = wqkv[(size_t)(k0 + r) * QKV3 + n0 + tx];
    __syncthreads();
#pragma unroll
    for (int r = ty; r < 32; r += 8) Wqkt[(size_t)(n0 + r) * DMODEL + k0 + tx] = tobf(tile[tx][r]);
  }
}

// ---------------- GEMM2: 64x128 tile, 512 blocks (2/CU, 2 waves/SIMD) --------
// 3-buffer LDS (12KB each), counted vmcnt(3), XCD-swizzled grid, swizzled LDS.
// Per-output-element accumulation chain identical to the 128x128 version.

__global__ __launch_bounds__(256) void k_gemm2(const bf16* __restrict__ A, const bf16* __restrict__ Bt,
                                               float* __restrict__ C, const float* __restrict__ bias,
                                               int M, int Nn, int K) {
  __shared__ __attribute__((aligned(16))) char smem[36864];  // 3 x (As 4KB | Bs 8KB)
  const int nTn = Nn >> 7;  // 8
  int nwg = gridDim.x;
  int bid = blockIdx.x;
  int wgs = (bid & 7) * (nwg >> 3) + (bid >> 3);  // bijective XCD swizzle (nwg%8==0)
  const int m0 = (wgs / nTn) << 6;
  const int n0 = (wgs % nTn) << 7;
  const int tid = threadIdx.x;
  const int lane = tid & 63, w = tid >> 6;
  const int wr = w >> 1, wc = w & 1;
  const int l15 = lane & 15, lhi = lane >> 4;
  f32x4 acc[2][4] = {};

  const int fA = tid * 16;  // A: 4KB, one inst/thread
  const int rA = fA >> 6;
  const int keA = (((fA & 63) >> 4) ^ ((rA >> 1) & 3)) << 3;
  const int fB0 = tid * 16, fB1 = fB0 + 4096;  // B: 8KB, two insts/thread
  const int rB0 = fB0 >> 6, rB1 = fB1 >> 6;
  const int keB0 = (((fB0 & 63) >> 4) ^ ((rB0 >> 1) & 3)) << 3;
  const int keB1 = (((fB1 & 63) >> 4) ^ ((rB1 >> 1) & 3)) << 3;
  const int rsw = ((l15 >> 1) & 3) << 3;

#define GSTAGE(bb_, k0_)                                                                       \
  do {                                                                                         \
    __builtin_amdgcn_global_load_lds(GPTR(A + (size_t)(m0 + rA) * K + (k0_) + keA),            \
                                     SPTR(smem + (bb_)*12288 + fA), 16, 0, 0);                 \
    __builtin_amdgcn_global_load_lds(GPTR(Bt + (size_t)(n0 + rB0) * K + (k0_) + keB0),         \
                                     SPTR(smem + (bb_)*12288 + 4096 + fB0), 16, 0, 0);         \
    __builtin_amdgcn_global_load_lds(GPTR(Bt + (size_t)(n0 + rB1) * K + (k0_) + keB1),         \
                                     SPTR(smem + (bb_)*12288 + 4096 + fB1), 16, 0, 0);         \
  } while (0)

  GSTAGE(0, 0);
  GSTAGE(1, 32);
  const int nIt = K >> 5;
  int bi = 0, b2 = 2;
  for (int it = 0; it < nIt; ++it) {
    if (it < nIt - 1) {
      asm volatile("s_waitcnt vmcnt(3)" ::: "memory");  // tile it done; it+1 in flight
    } else {
      asm volatile("s_waitcnt vmcnt(0)" ::: "memory");
    }
    __builtin_amdgcn_s_barrier();
    if (it + 2 < nIt) GSTAGE(b2, (it + 2) << 5);
    const bf16* As = (const bf16*)(smem + bi * 12288);
    const bf16* Bs = (const bf16*)(smem + bi * 12288 + 4096);
    bf16x8 af[2], bfv[4];
#pragma unroll
    for (int i = 0; i < 2; ++i)
      af[i] = *(const bf16x8*)(As + (wr * 32 + i * 16 + l15) * 32 + ((lhi << 3) ^ rsw));
#pragma unroll
    for (int j = 0; j < 4; ++j)
      bfv[j] = *(const bf16x8*)(Bs + (wc * 64 + j * 16 + l15) * 32 + ((lhi << 3) ^ rsw));
    __builtin_amdgcn_s_setprio(1);
#pragma unroll
    for (int i = 0; i < 2; ++i)
#pragma unroll
      for (int j = 0; j < 4; ++j) acc[i][j] = mfma16(af[i], bfv[j], acc[i][j]);
    __builtin_amdgcn_s_setprio(0);
    bi = (bi == 2) ? 0 : bi + 1;
    b2 = (b2 == 2) ? 0 : b2 + 1;
  }
#undef GSTAGE

  float bj[4];
#pragma unroll
  for (int j = 0; j < 4; ++j) bj[j] = bias[n0 + wc * 64 + j * 16 + l15];
#pragma unroll
  for (int i = 0; i < 2; ++i)
#pragma unroll
    for (int j = 0; j < 4; ++j) {
      int row = m0 + wr * 32 + i * 16 + lhi * 4;
      int col = n0 + wc * 64 + j * 16 + l15;
#pragma unroll
      for (int r = 0; r < 4; ++r) C[(size_t)(row + r) * Nn + col] = acc[i][j][r] + bj[j];
    }
}

// ---------------- GEMM1 fused: X x Wqkv^T -> RoPE(Q), RoPE(K), V^T ----------
// Blocks [0,768): GEMM + fused epilogue (unscaled cs table, round-13 numerics).
// Blocks [768,1792): w_out transpose tiles.

__global__ __launch_bounds__(256) void k_gemm1f(const bf16* __restrict__ A, const bf16* __restrict__ Bt,
                                                const float* __restrict__ cs,
                                                const float* __restrict__ wout, bf16* __restrict__ Woutt,
                                                bf16* __restrict__ Qr, bf16* __restrict__ Kr,
                                                bf16* __restrict__ Vt) {
  constexpr int K = DMODEL, Nn = QKV3;
  constexpr int NG = (MTOK / 128) * (QKV3 / 128);  // 768 GEMM blocks
  __shared__ __attribute__((aligned(16))) char smem[49152];
  int bid = blockIdx.x;
  const int tid = threadIdx.x;

  if (bid >= NG) {
    float* tile = (float*)smem;  // [32][33]
    int t = bid - NG;            // [0, 1024)
    int n0 = (t & 31) * 32, k0 = (t >> 5) * 32;
    int tx = tid & 31, ty = tid >> 5;
#pragma unroll
    for (int r = ty; r < 32; r += 8) tile[r * 33 + tx] = wout[(size_t)(k0 + r) * DMODEL + n0 + tx];
    __syncthreads();
#pragma unroll
    for (int r = ty; r < 32; r += 8) Woutt[(size_t)(n0 + r) * DMODEL + k0 + tx] = tobf(tile[tx * 33 + r]);
    return;
  }

  const int nTn = Nn >> 7;  // 24
  int wgs = (bid & 7) * (NG >> 3) + (bid >> 3);
  const int m0 = (wgs / nTn) << 7;
  const int n0 = (wgs % nTn) << 7;
  const int lane = tid & 63, w = tid >> 6;
  const int wr = w >> 1, wc = w & 1;
  const int l15 = lane & 15, lhi = lane >> 4;
  f32x4 acc[4][4] = {};

  const int flat0 = w * 1024 + lane * 16;
  const int flat1 = flat0 + 4096;
  const int row0 = flat0 >> 6, row1 = flat1 >> 6;
  const int ke0 = (((flat0 & 63) >> 4) ^ ((row0 >> 1) & 3)) << 3;
  const int ke1 = (((flat1 & 63) >> 4) ^ ((row1 >> 1) & 3)) << 3;
  const int rsw = ((l15 >> 1) & 3) << 3;

#define GSTAGE(bb_, k0_)                                                                       \
  do {                                                                                         \
    __builtin_amdgcn_global_load_lds(GPTR(A + (size_t)(m0 + row0) * K + (k0_) + ke0),          \
                                     SPTR(smem + (bb_)*16384 + flat0), 16, 0, 0);              \
    __builtin_amdgcn_global_load_lds(GPTR(A + (size_t)(m0 + row1) * K + (k0_) + ke1),          \
                                     SPTR(smem + (bb_)*16384 + flat1), 16, 0, 0);              \
    __builtin_amdgcn_global_load_lds(GPTR(Bt + (size_t)(n0 + row0) * K + (k0_) + ke0),         \
                                     SPTR(smem + (bb_)*16384 + 8192 + flat0), 16, 0, 0);       \
    __builtin_amdgcn_global_load_lds(GPTR(Bt + (size_t)(n0 + row1) * K + (k0_) + ke1),         \
                                     SPTR(smem + (bb_)*16384 + 8192 + flat1), 16, 0, 0);       \
  } while (0)

  GSTAGE(0, 0);
  GSTAGE(1, 32);
  const int nIt = K >> 5;  // 32
  int bi = 0, b2 = 2;
  for (int it = 0; it < nIt; ++it) {
    if (it < nIt - 1) {
      asm volatile("s_waitcnt vmcnt(4)" ::: "memory");
    } else {
      asm volatile("s_waitcnt vmcnt(0)" ::: "memory");
    }
    __builtin_amdgcn_s_barrier();
    if (it + 2 < nIt) GSTAGE(b2, (it + 2) << 5);
    const bf16* As = (const bf16*)(smem + bi * 16384);
    const bf16* Bs = (const bf16*)(smem + bi * 16384 + 8192);
    bf16x8 af[4], bfv[4];
#pragma unroll
    for (int i = 0; i < 4; ++i) {
      af[i] = *(const bf16x8*)(As + (wr * 64 + i * 16 + l15) * 32 + ((lhi << 3) ^ rsw));
      bfv[i] = *(const bf16x8*)(Bs + (wc * 64 + i * 16 + l15) * 32 + ((lhi << 3) ^ rsw));
    }
    __builtin_amdgcn_s_setprio(1);
#pragma unroll
    for (int i = 0; i < 4; ++i)
#pragma unroll
      for (int j = 0; j < 4; ++j) acc[i][j] = mfma16(af[i], bfv[j], acc[i][j]);
    __builtin_amdgcn_s_setprio(0);
    bi = (bi == 2) ? 0 : bi + 1;
    b2 = (b2 == 2) ? 0 : b2 + 1;
  }
#undef GSTAGE

  __syncthreads();
  const int part = n0 >> 10;  // 0=q, 1=k, 2=v
  const int b = m0 >> 11;

  if (part < 2) {
    bf16* Cs = (bf16*)smem;  // [128][128]
#pragma unroll
    for (int i = 0; i < 4; ++i)
#pragma unroll
      for (int j = 0; j < 4; ++j) {
        int row = wr * 64 + i * 16 + lhi * 4;
        int col = wc * 64 + j * 16 + l15;
#pragma unroll
        for (int r = 0; r < 4; ++r) Cs[(row + r) * 128 + col] = tobf(acc[i][j][r]);
      }
    __syncthreads();
    bf16* dst = part == 0 ? Qr : Kr;
#pragma unroll
    for (int inst = 0; inst < 8; ++inst) {
      int flat = inst * 4096 + tid * 16;
      int row = flat >> 8, c0 = (flat & 255) >> 1;
      int n = (m0 + row) & 2047;
      int gc = (n0 & 1023) + c0;
      int h = gc >> 6, d0 = gc & 63;
      u32x4 v = *(const u32x4*)(smem + flat);
      const float* cp = cs + (((n << 5) + (d0 >> 1)) << 1);
      f32x4 csA = *(const f32x4*)cp;
      f32x4 csB = *(const f32x4*)(cp + 4);
      u32x4 ow;
#pragma unroll
      for (int j = 0; j < 4; ++j) {
        float cc = (j == 0) ? csA[0] : (j == 1) ? csA[2] : (j == 2) ? csB[0] : csB[2];
        float sn = (j == 0) ? csA[1] : (j == 1) ? csA[3] : (j == 2) ? csB[1] : csB[3];
        u32 pw = v[j];
        u32 tl = pw << 16, th = pw & 0xffff0000u;
        float a0, a1;
        __builtin_memcpy(&a0, &tl, 4);
        __builtin_memcpy(&a1, &th, 4);
        bf16 o0 = tobf(a0 * cc - a1 * sn);
        bf16 o1 = tobf(a1 * cc + a0 * sn);
        unsigned short u0, u1;
        __builtin_memcpy(&u0, &o0, 2);
        __builtin_memcpy(&u1, &o1, 2);
        ow[j] = (u32)u0 | ((u32)u1 << 16);
      }
      *(u32x4*)(dst + (((size_t)(b * 16 + h) * 2048 + n) << 6) + d0) = ow;
    }
  } else {
#pragma unroll
    for (int i = 0; i < 4; ++i)
#pragma unroll
      for (int j = 0; j < 4; ++j) {
        int col = wc * 64 + j * 16 + l15;
#pragma unroll
        for (int r = 0; r < 4; ++r) {
          int row = wr * 64 + i * 16 + lhi * 4 + r;
          int byte = (col << 8) + ((((row >> 3) ^ (col & 7)) << 4) | ((row & 7) << 1));
          *(bf16*)(smem + byte) = tobf(acc[i][j][r]);
        }
      }
    __syncthreads();
#pragma unroll
    for (int inst = 0; inst < 8; ++inst) {
      int flat = inst * 4096 + tid * 16;
      int c = flat >> 8;
      int rr0 = (flat & 255) >> 1;
      u32x4 vv = *(const u32x4*)(smem + (c << 8) + ((((rr0 >> 3) ^ (c & 7)) << 4)));
      int gc = (n0 & 1023) + c;
      int h = gc >> 6, dd = gc & 63;
      *(u32x4*)(Vt + (((size_t)(b * 16 + h) * 64 + dd) << 11) + (m0 & 2047) + rr0) = vv;
    }
  }
}

// ---------------- Flash attention (round-13 numerics: fmaf(st,sc,-FOFF)) ----
__global__ __launch_bounds__(512, 4) void k_attn(const bf16* __restrict__ Qr,
                                                 const bf16* __restrict__ Kr,
                                                 const bf16* __restrict__ Vt,
                                                 bf16* __restrict__ AO) {
  __shared__ __attribute__((aligned(16))) char lds[2][40960];
  int wg = blockIdx.x;
  int work = (wg & 7) * 64 + (wg >> 3);
  int qc = work & 15, h = (work >> 4) & 15, b = work >> 8;
  int tid = threadIdx.x;
  int wv = tid >> 6, lane = tid & 63;
  int pipe = wv >> 2, wsub = wv & 3;
  int l31 = lane & 31, h5 = lane >> 5;
  int q0 = qc * 128 + wsub * 32;
  int kbase = pipe << 10;
  const bf16* Qb = Qr + ((size_t)(b * NH + h)) * SEQ * 64;
  const bf16* Kb = Kr + ((size_t)(b * NH + h)) * SEQ * 64;
  const bf16* Vb = Vt + ((size_t)(b * NH + h)) * 64 * SEQ;
  char* pb = lds[pipe];

  int ptid = tid & 255;
  int sf0 = ptid * 16, sf1 = 4096 + ptid * 16;
  int sr0 = sf0 >> 7, sr1 = sf1 >> 7;
  int sc0 = (sf0 & 127) ^ ((sr0 & 7) << 4);
  int sc1 = (sf1 & 127) ^ ((sr1 & 7) << 4);
  size_t kgb0 = (size_t)sr0 * 64 + (sc0 >> 1), kgb1 = (size_t)sr1 * 64 + (sc1 >> 1);
  size_t vgb0 = (size_t)sr0 * SEQ + (sc0 >> 1), vgb1 = (size_t)sr1 * SEQ + (sc1 >> 1);

#define STAGE_K(bi_, kb_)                                                                     \
  do {                                                                                        \
    size_t ko_ = (size_t)(kbase + (kb_));                                                     \
    char* bb_ = pb + (bi_)*8192;                                                              \
    __builtin_amdgcn_global_load_lds(GPTR(Kb + ko_ * 64 + kgb0), SPTR(bb_ + sf0), 16, 0, 0);  \
    __builtin_amdgcn_global_load_lds(GPTR(Kb + ko_ * 64 + kgb1), SPTR(bb_ + sf1), 16, 0, 0);  \
  } while (0)
#define STAGE_V(bi_, kb_)                                                                     \
  do {                                                                                        \
    size_t ko_ = (size_t)(kbase + (kb_));                                                     \
    char* bb_ = pb + 24576 + (bi_)*8192;                                                      \
    __builtin_amdgcn_global_load_lds(GPTR(Vb + ko_ + vgb0), SPTR(bb_ + sf0), 16, 0, 0);       \
    __builtin_amdgcn_global_load_lds(GPTR(Vb + ko_ + vgb1), SPTR(bb_ + sf1), 16, 0, 0);       \
  } while (0)

  bf16x8 qf[4];
#pragma unroll
  for (int s = 0; s < 4; ++s) qf[s] = *(const bf16x8*)(Qb + (q0 + l31) * 64 + s * 16 + h5 * 8);

  f32x16 acc0 = {}, acc1 = {};
#if HAVE_DOT2
  float sacc0 = 0.f, sacc1 = 0.f, sacc2 = 0.f, sacc3 = 0.f;
  const bf16x2 ones2 = {(bf16)1.0f, (bf16)1.0f};
#else
  float ssum_run = 0.f;
#endif
  const float sc = 0.125f * 1.44269504f;
  const float FOFF = 8.0f;
  const int sw = (l31 & 7) << 4;
  const int cbase = h5 * 16;

  STAGE_K(0, 0);
  STAGE_V(0, 0);
  STAGE_K(1, 64);

  constexpr int NT = (SEQ / 2) / 64;
  int kc = 0, kc2 = 2;
  for (int t = 0; t < NT; ++t) {
    if (t < NT - 1) {
      asm volatile("s_waitcnt vmcnt(2)" ::: "memory");
    } else {
      asm volatile("s_waitcnt vmcnt(0)" ::: "memory");
    }
    __builtin_amdgcn_s_barrier();
    if (t + 1 < NT) STAGE_V((t + 1) & 1, (t + 1) * 64);
    if (t + 2 < NT) STAGE_K(kc2, (t + 2) * 64);
    char* cbK = pb + kc * 8192;
    char* cbV = pb + 24576 + (t & 1) * 8192;
    kc = (kc == 2) ? 0 : kc + 1;
    kc2 = (kc2 == 2) ? 0 : kc2 + 1;

    f32x16 st0 = {}, st1 = {};
    __builtin_amdgcn_s_setprio(1);
#pragma unroll
    for (int s = 0; s < 4; ++s) {
      bf16x8 kf0 = *(const bf16x8*)(cbK + l31 * 128 + ((s * 32 + cbase) ^ sw));
      bf16x8 kf1 = *(const bf16x8*)(cbK + 4096 + l31 * 128 + ((s * 32 + cbase) ^ sw));
      st0 = mfma32(kf0, qf[s], st0);
      st1 = mfma32(kf1, qf[s], st1);
    }
    __builtin_amdgcn_s_setprio(0);

    float p[32];
#pragma unroll
    for (int r = 0; r < 16; ++r) p[r] = __builtin_amdgcn_exp2f(fmaf(st0[r], sc, -FOFF));
#pragma unroll
    for (int r = 0; r < 16; ++r) p[16 + r] = __builtin_amdgcn_exp2f(fmaf(st1[r], sc, -FOFF));

    u32 P32[16];
#pragma unroll
    for (int i = 0; i < 16; ++i) {
      bf16 lo = tobf(p[2 * i]), hi = tobf(p[2 * i + 1]);
      unsigned short ul, uh;
      __builtin_memcpy(&ul, &lo, 2);
      __builtin_memcpy(&uh, &hi, 2);
      P32[i] = (u32)ul | ((u32)uh << 16);
    }

#if HAVE_DOT2
#pragma unroll
    for (int i = 0; i < 16; i += 4) {
      sacc0 = __builtin_amdgcn_fdot2_f32_bf16(__builtin_bit_cast(bf16x2, P32[i]), ones2, sacc0, false);
      sacc1 = __builtin_amdgcn_fdot2_f32_bf16(__builtin_bit_cast(bf16x2, P32[i + 1]), ones2, sacc1, false);
      sacc2 = __builtin_amdgcn_fdot2_f32_bf16(__builtin_bit_cast(bf16x2, P32[i + 2]), ones2, sacc2, false);
      sacc3 = __builtin_amdgcn_fdot2_f32_bf16(__builtin_bit_cast(bf16x2, P32[i + 3]), ones2, sacc3, false);
    }
#else
    {
      float sm[16];
#pragma unroll
      for (int i = 0; i < 16; ++i) {
        u32 ulo = P32[i] << 16, uhi = P32[i] & 0xffff0000u;
        float flo, fhi;
        __builtin_memcpy(&flo, &ulo, 4);
        __builtin_memcpy(&fhi, &uhi, 4);
        sm[i] = flo + fhi;
      }
#pragma unroll
      for (int off = 8; off > 0; off >>= 1)
#pragma unroll
        for (int r = 0; r < off; ++r) sm[r] += sm[r + off];
      ssum_run += sm[0];
    }
#endif

#if !HAVE_PLSWAP
    const int evens[8] = {0, 1, 4, 5, 8, 9, 12, 13};
    const int odds[8] = {2, 3, 6, 7, 10, 11, 14, 15};
    u32 recv[8];
#pragma unroll
    for (int j = 0; j < 8; ++j) {
      u32 sv = h5 ? P32[evens[j]] : P32[odds[j]];
      recv[j] = (u32)__shfl_xor((int)sv, 32, 64);
    }
#endif

    __builtin_amdgcn_s_setprio(1);
#pragma unroll
    for (int s2 = 0; s2 < 4; ++s2) {
      int x0 = ((s2 >> 1) << 3) + ((s2 & 1) << 2);  // 0,4,8,12
#if HAVE_PLSWAP
      u32x2 r02 = __builtin_amdgcn_permlane32_swap(P32[x0], P32[x0 + 2], false, false);
      u32x2 r13 = __builtin_amdgcn_permlane32_swap(P32[x0 + 1], P32[x0 + 3], false, false);
      u32x4 wv4 = {r02.x, r13.x, r02.y, r13.y};
#else
      u32 w0 = h5 ? recv[2 * s2] : P32[x0];
      u32 w1 = h5 ? recv[2 * s2 + 1] : P32[x0 + 1];
      u32 w2 = h5 ? P32[x0 + 2] : recv[2 * s2];
      u32 w3 = h5 ? P32[x0 + 3] : recv[2 * s2 + 1];
      u32x4 wv4 = {w0, w1, w2, w3};
#endif
      bf16x8 pfr = __builtin_bit_cast(bf16x8, wv4);
      bf16x8 vf0 = *(const bf16x8*)(cbV + l31 * 128 + ((s2 * 32 + cbase) ^ sw));
      bf16x8 vf1 = *(const bf16x8*)(cbV + 4096 + l31 * 128 + ((s2 * 32 + cbase) ^ sw));
      acc0 = mfma32(vf0, pfr, acc0);
      acc1 = mfma32(vf1, pfr, acc1);
    }
    __builtin_amdgcn_s_setprio(0);
  }

#if HAVE_DOT2
  float ssum = (sacc0 + sacc1) + (sacc2 + sacc3);
#else
  float ssum = ssum_run;
#endif

  __syncthreads();
  float* cacc = (float*)&lds[0][0];
  float* csum = (float*)(&lds[0][0] + 36864);
  int slot = (wsub * 64 + lane) * 36;
  if (pipe == 1) {
#pragma unroll
    for (int r = 0; r < 16; r += 4) {
      *(f32x4*)(cacc + slot + r) = f32x4{acc0[r], acc0[r + 1], acc0[r + 2], acc0[r + 3]};
      *(f32x4*)(cacc + slot + 16 + r) = f32x4{acc1[r], acc1[r + 1], acc1[r + 2], acc1[r + 3]};
    }
    csum[wsub * 64 + lane] = ssum;
  }
  __syncthreads();
  if (pipe == 0) {
#pragma unroll
    for (int r = 0; r < 16; r += 4) {
      f32x4 v0 = *(const f32x4*)(cacc + slot + r);
      f32x4 v1 = *(const f32x4*)(cacc + slot + 16 + r);
#pragma unroll
      for (int j = 0; j < 4; ++j) { acc0[r + j] += v0[j]; acc1[r + j] += v1[j]; }
    }
    ssum += csum[wsub * 64 + lane];
    ssum += __shfl_xor(ssum, 32, 64);
    float inv = 1.0f / ssum;
    size_t tok = (size_t)(b * SEQ + q0 + l31);
#pragma unroll
    for (int a = 0; a < 4; ++a) {
      bf16x4 ov0, ov1;
#pragma unroll
      for (int j = 0; j < 4; ++j) {
        ov0[j] = tobf(acc0[4 * a + j] * inv);
        ov1[j] = tobf(acc1[4 * a + j] * inv);
      }
      *(bf16x4*)(AO + tok * (NH * HD) + h * 64 + 8 * a + 4 * h5) = ov0;
      *(bf16x4*)(AO + tok * (NH * HD) + h * 64 + 32 + 8 * a + 4 * h5) = ov1;
    }
  }
#undef STAGE_K
#undef STAGE_V
}

// ---------------- launcher ----------------

extern "C" void kernel_launch(void* const* d_in, const int* in_sizes, int n_in,
                              void* d_out, int out_size, void* d_ws, size_t ws_size,
                              hipStream_t stream) {
  const float* hs = (const float*)d_in[0];
  const float* wqkv = (const float*)d_in[1];
  const float* wout = (const float*)d_in[2];
  const float* bout = (const float*)d_in[3];
  char* ws = (char*)d_ws;
  bf16* Xb = (bf16*)(ws + OXB);
  bf16* Wqkt = (bf16*)(ws + OWQ);
  bf16* Woutt = (bf16*)(ws + OWO);
  float* cs = (float*)(ws + OCS);
  bf16* Qr = (bf16*)(ws + OQR);
  bf16* Kr = (bf16*)(ws + OKR);
  bf16* Vt = (bf16*)(ws + OVT);
  bf16* AO = (bf16*)(ws + OAO);

  k_prep<<<7424, 256, 0, stream>>>(hs, wqkv, cs, Xb, Wqkt);
  k_gemm1f<<<(MTOK / 128) * (QKV3 / 128) + 1024, 256, 0, stream>>>(Xb, Wqkt, cs, wout, Woutt, Qr, Kr, Vt);
  k_attn<<<BATCH * NH * (SEQ / 128), 512, 0, stream>>>(Qr, Kr, Vt, AO);
  k_gemm2<<<(MTOK / 64) * (DMODEL / 128), 256, 0, stream>>>(AO, Woutt, (float*)d_out, bout, MTOK, DMODEL, DMODEL);
}